// Round 1
// baseline (824.336 us; speedup 1.0000x reference)
//
#include <hip/hip_runtime.h>
#include <hip/hip_bf16.h>
#include <cmath>
#include <cstdint>

typedef __bf16 bf16;
typedef __bf16 bf16x8 __attribute__((ext_vector_type(8)));
typedef __bf16 bf16x4 __attribute__((ext_vector_type(4)));
typedef float  f32x4  __attribute__((ext_vector_type(4)));

constexpr int B_   = 4;
constexpr int S_   = 2048;
constexpr int D_   = 1024;
constexpr int H_   = 16;
constexpr int HD_  = 64;
constexpr int DFF_ = 4096;
constexpr int TD_  = 256;
constexpr int KEEP = 1433;             // int(2048*0.7)
constexpr int M_TOT = B_ * KEEP;       // 5732
constexpr int MPAD  = 5760;            // 45*128
constexpr int QT    = (KEEP + 15) / 16; // 90
constexpr float EPS = 1e-5f;

__device__ __forceinline__ f32x4 mfma16(bf16x8 a, bf16x8 b, f32x4 c) {
  return __builtin_amdgcn_mfma_f32_16x16x32_bf16(a, b, c, 0, 0, 0);
}

#define GLOAD_LDS(gp, lp)                                                     \
  __builtin_amdgcn_global_load_lds(                                           \
      (const __attribute__((address_space(1))) void*)(gp),                    \
      (__attribute__((address_space(3))) void*)(lp), 16, 0, 0)

// ---------------- token importance (fp64 accumulation for exact ranking) ----
__global__ __launch_bounds__(256) void k_importance(
    const float* __restrict__ x, const float* __restrict__ w1,
    const float* __restrict__ b1, const float* __restrict__ w2,
    const float* __restrict__ b2, double* __restrict__ imp)
{
  const int tok = blockIdx.x;            // b*S + s
  const float* xr = x + (size_t)tok * D_;
  __shared__ float xs[D_];
  __shared__ double part[8][32];
  __shared__ double sacc[32];
  const int t = threadIdx.x;
  for (int i = t; i < D_ / 4; i += 256)
    ((float4*)xs)[i] = ((const float4*)xr)[i];
  __syncthreads();
  const int o = t & 31;       // which of 32 hidden units
  const int ck = t >> 5;      // 0..7 chunk of 128 cols
  const float* wr = w1 + (size_t)o * D_ + ck * 128;
  const float* xc = xs + ck * 128;
  double acc = 0.0;
  for (int c = 0; c < 128; ++c) acc += (double)xc[c] * (double)wr[c];
  part[ck][o] = acc;
  __syncthreads();
  if (t < 32) {
    double s = 0.0;
    for (int c = 0; c < 8; ++c) s += part[c][t];
    s += (double)b1[t];
    double sv = s / (1.0 + exp(-s));    // silu
    sacc[t] = sv * (double)w2[t];
  }
  __syncthreads();
  if (t == 0) {
    double r = 0.0;
    for (int i = 0; i < 32; ++i) r += sacc[i];
    imp[tok] = r + (double)b2[0];
  }
}

// ---------------- rank each token: # of (greater) or (equal && earlier) -----
__global__ __launch_bounds__(256) void k_rank(const double* __restrict__ imp,
                                              int* __restrict__ rank)
{
  const int b = blockIdx.x >> 3;
  const int seg = blockIdx.x & 7;
  __shared__ double vals[S_];
  const double* ib = imp + (size_t)b * S_;
  for (int i = threadIdx.x; i < S_; i += 256) vals[i] = ib[i];
  __syncthreads();
  const int s = seg * 256 + threadIdx.x;
  const double v = vals[s];
  int cnt = 0;
  for (int j = 0; j < S_; ++j) {
    double u = vals[j];
    cnt += (u > v) || (u == v && j < s);
  }
  rank[b * S_ + s] = cnt;
}

// ---------------- compact kept indices (ascending) ---------------------------
__global__ __launch_bounds__(256) void k_compact(const int* __restrict__ rank,
                                                 int* __restrict__ idx)
{
  const int b = blockIdx.x;
  __shared__ int wcnt[4];
  __shared__ int base_s;
  if (threadIdx.x == 0) base_s = 0;
  __syncthreads();
  const int t = threadIdx.x, lane = t & 63, w = t >> 6;
  for (int c = 0; c < S_ / 256; ++c) {
    const int s = c * 256 + t;
    const bool kept = rank[b * S_ + s] < KEEP;
    unsigned long long m = __ballot(kept);
    int piw = __popcll(m & ((1ull << lane) - 1ull));
    if (lane == 0) wcnt[w] = __popcll(m);
    __syncthreads();
    int off = base_s;
    for (int i = 0; i < w; ++i) off += wcnt[i];
    if (kept) idx[b * KEEP + off + piw] = s;
    __syncthreads();
    if (t == 0) base_s += wcnt[0] + wcnt[1] + wcnt[2] + wcnt[3];
    __syncthreads();
  }
}

// ---------------- cond projection: p = silu(t_emb) @ W.T + b ----------------
__global__ __launch_bounds__(256) void k_condproj(
    const float* __restrict__ temb, const float* __restrict__ W,
    const float* __restrict__ bias, float* __restrict__ p)
{
  const int gw = (int)((blockIdx.x * 256 + threadIdx.x) >> 6);
  const int lane = threadIdx.x & 63;
  const int b = gw >> 11;          // 2048 outputs per batch
  const int row = gw & 2047;
  const float* te = temb + (size_t)b * TD_;
  const float* wr = W + (size_t)row * TD_;
  float acc = 0.f;
  for (int i = lane; i < TD_; i += 64) {
    float c = te[i];
    acc += (c / (1.f + __expf(-c))) * wr[i];
  }
  for (int o = 32; o > 0; o >>= 1) acc += __shfl_down(acc, o);
  if (lane == 0) p[(size_t)b * 2 * D_ + row] = acc + bias[row];
}

// ---------------- fp32 -> bf16 weight cast ----------------------------------
__global__ void k_f2b(const float* __restrict__ src, bf16* __restrict__ dst, int n4)
{
  int i = blockIdx.x * 256 + threadIdx.x;
  if (i < n4) {
    float4 v = ((const float4*)src)[i];
    bf16x4 o = {(bf16)v.x, (bf16)v.y, (bf16)v.z, (bf16)v.w};
    ((bf16x4*)dst)[i] = o;
  }
}

// ---------------- gather + adaLN -> bf16 -------------------------------------
__global__ __launch_bounds__(256) void k_adaln(
    const float* __restrict__ xsrc, const int* __restrict__ idx,
    const float* __restrict__ p, bf16* __restrict__ hout)
{
  const int r = blockIdx.x, t = threadIdx.x;
  bf16* orow = hout + (size_t)r * D_;
  if (r >= M_TOT) {
    bf16x4 z = {(bf16)0.f, (bf16)0.f, (bf16)0.f, (bf16)0.f};
    ((bf16x4*)orow)[t] = z;
    return;
  }
  const int b = r / KEEP, j = r - b * KEEP;
  const int s = idx[b * KEEP + j];
  const float* xr = xsrc + ((size_t)(b * S_ + s)) * D_;
  float4 v = ((const float4*)xr)[t];
  __shared__ float red[8];
  float sum = v.x + v.y + v.z + v.w;
  for (int o = 32; o > 0; o >>= 1) sum += __shfl_down(sum, o);
  const int lane = t & 63, w = t >> 6;
  if (lane == 0) red[w] = sum;
  __syncthreads();
  const float mu = (red[0] + red[1] + red[2] + red[3]) * (1.f / D_);
  const float dx = v.x - mu, dy = v.y - mu, dz = v.z - mu, dw = v.w - mu;
  float vs = dx * dx + dy * dy + dz * dz + dw * dw;
  for (int o = 32; o > 0; o >>= 1) vs += __shfl_down(vs, o);
  if (lane == 0) red[4 + w] = vs;
  __syncthreads();
  const float rstd = rsqrtf((red[4] + red[5] + red[6] + red[7]) * (1.f / D_) + EPS);
  const float* gp = p + (size_t)b * 2 * D_;
  float4 g  = ((const float4*)gp)[t];
  float4 be = ((const float4*)(gp + D_))[t];
  bf16x4 o;
  o[0] = (bf16)(dx * rstd * (1.f + g.x) + be.x);
  o[1] = (bf16)(dy * rstd * (1.f + g.y) + be.y);
  o[2] = (bf16)(dz * rstd * (1.f + g.z) + be.z);
  o[3] = (bf16)(dw * rstd * (1.f + g.w) + be.w);
  ((bf16x4*)orow)[t] = o;
}

// ---------------- GEMM: C[m][n] = sum_k A[m][k] * W[n][k]  (+ epilogues) -----
// MODE 0: bias -> bf16 out. MODE 1: bias+gelu -> bf16 out.
// MODE 2: bias, then d_out[row(m)][n] += gate[n]*v (gathered residual).
template <int MODE>
__global__ __launch_bounds__(256) void k_gemm(
    const bf16* __restrict__ A, const bf16* __restrict__ W,
    const float* __restrict__ bias, bf16* __restrict__ Cbf,
    const float* __restrict__ gate, const int* __restrict__ idx,
    float* __restrict__ resid, int N, int K)
{
  __shared__ bf16 As[128 * 32];
  __shared__ bf16 Ws[128 * 32];
  const int t = threadIdx.x, lane = t & 63;
  const int w = t >> 6, wr = w >> 1, wc = w & 1;
  const int fr = lane & 15, fq = lane >> 4;
  const int bm = blockIdx.y, bn = blockIdx.x;
  const bf16* Ab = A + (size_t)bm * 128 * K;
  const bf16* Wb = W + (size_t)bn * 128 * K;
  f32x4 acc[4][4] = {};
  for (int kt = 0; kt < K; kt += 32) {
#pragma unroll
    for (int it = 0; it < 2; ++it) {
      int e = it * 256 + t;
      int row = e >> 2, c = e & 3;
      GLOAD_LDS(Ab + (size_t)row * K + kt + c * 8, As + (size_t)e * 8);
      GLOAD_LDS(Wb + (size_t)row * K + kt + c * 8, Ws + (size_t)e * 8);
    }
    __syncthreads();
    bf16x8 af[4], wf[4];
#pragma unroll
    for (int i = 0; i < 4; ++i) {
      af[i] = *(const bf16x8*)(As + (wr * 64 + i * 16 + fr) * 32 + fq * 8);
      wf[i] = *(const bf16x8*)(Ws + (wc * 64 + i * 16 + fr) * 32 + fq * 8);
    }
#pragma unroll
    for (int i = 0; i < 4; ++i)
#pragma unroll
      for (int j = 0; j < 4; ++j)
        acc[i][j] = mfma16(af[i], wf[j], acc[i][j]);
    __syncthreads();
  }
#pragma unroll
  for (int i = 0; i < 4; ++i) {
#pragma unroll
    for (int j = 0; j < 4; ++j) {
#pragma unroll
      for (int r = 0; r < 4; ++r) {
        const int m = bm * 128 + wr * 64 + i * 16 + fq * 4 + r;
        const int n = bn * 128 + wc * 64 + j * 16 + fr;
        float v = acc[i][j][r] + bias[n];
        if (MODE == 0) {
          Cbf[(size_t)m * N + n] = (bf16)v;
        } else if (MODE == 1) {
          float gl = 0.5f * v * (1.f + erff(v * 0.70710678118654752f));
          Cbf[(size_t)m * N + n] = (bf16)gl;
        } else {
          if (m < M_TOT) {
            const int b = m / KEEP, jj = m - b * KEEP;
            const int s = idx[b * KEEP + jj];
            resid[((size_t)(b * S_ + s)) * D_ + n] += gate[n] * v;
          }
        }
      }
    }
  }
}

// ---------------- flash attention: 1 wave per (b, h, 16 q-rows) --------------
__global__ __launch_bounds__(64) void k_attn(const bf16* __restrict__ qkv,
                                             bf16* __restrict__ out)
{
  __shared__ bf16 plds[16 * 32];
  const int lane = threadIdx.x;
  const int fr = lane & 15, fq = lane >> 4;
  int id = blockIdx.x;
  const int qt = id % QT; id /= QT;
  const int h = id % H_;
  const int b = id / H_;
  const size_t rowbase = (size_t)b * KEEP;
  const int j0 = qt * 16;
  const size_t RS = 3 * D_;   // qkv row stride (elements)
  const bf16* qp = qkv + (rowbase + j0 + fr) * RS + h * HD_ + fq * 8;
  const bf16x8 qf0 = *(const bf16x8*)qp;
  const bf16x8 qf1 = *(const bf16x8*)(qp + 32);
  const bf16* kbase = qkv + rowbase * RS + D_ + h * HD_;
  const bf16* vbase = qkv + rowbase * RS + 2 * D_ + h * HD_;
  f32x4 o[4] = {};
  float mrow[4] = {-INFINITY, -INFINITY, -INFINITY, -INFINITY};
  float lrow[4] = {0.f, 0.f, 0.f, 0.f};
  for (int kv = 0; kv < KEEP; kv += 32) {
    f32x4 sc0 = {0.f, 0.f, 0.f, 0.f}, sc1 = {0.f, 0.f, 0.f, 0.f};
    {
      const bf16* kp0 = kbase + (size_t)(kv + fr) * RS + fq * 8;
      sc0 = mfma16(qf0, *(const bf16x8*)kp0, sc0);
      sc0 = mfma16(qf1, *(const bf16x8*)(kp0 + 32), sc0);
      const bf16* kp1 = kbase + (size_t)(kv + 16 + fr) * RS + fq * 8;
      sc1 = mfma16(qf0, *(const bf16x8*)kp1, sc1);
      sc1 = mfma16(qf1, *(const bf16x8*)(kp1 + 32), sc1);
    }
    const bool va = (kv + fr) < KEEP;
    const bool vb = (kv + 16 + fr) < KEEP;
    float fac[4];
#pragma unroll
    for (int r = 0; r < 4; ++r) {
      float s0 = va ? sc0[r] * 0.125f : -INFINITY;
      float s1 = vb ? sc1[r] * 0.125f : -INFINITY;
      float mx = fmaxf(s0, s1);
      mx = fmaxf(mx, __shfl_xor(mx, 1));
      mx = fmaxf(mx, __shfl_xor(mx, 2));
      mx = fmaxf(mx, __shfl_xor(mx, 4));
      mx = fmaxf(mx, __shfl_xor(mx, 8));
      const float mnew = fmaxf(mrow[r], mx);
      const float p0 = __expf(s0 - mnew);
      const float p1 = __expf(s1 - mnew);
      float rs = p0 + p1;
      rs += __shfl_xor(rs, 1);
      rs += __shfl_xor(rs, 2);
      rs += __shfl_xor(rs, 4);
      rs += __shfl_xor(rs, 8);
      const float f = __expf(mrow[r] - mnew);
      lrow[r] = lrow[r] * f + rs;
      mrow[r] = mnew;
      fac[r] = f;
      const int q = fq * 4 + r;
      plds[q * 32 + fr] = (bf16)p0;
      plds[q * 32 + 16 + fr] = (bf16)p1;
    }
#pragma unroll
    for (int db = 0; db < 4; ++db) {
      o[db][0] *= fac[0]; o[db][1] *= fac[1];
      o[db][2] *= fac[2]; o[db][3] *= fac[3];
    }
    __syncthreads();
    const bf16x8 pf = *(const bf16x8*)(plds + fr * 32 + fq * 8);
#pragma unroll
    for (int db = 0; db < 4; ++db) {
      bf16x8 vf;
#pragma unroll
      for (int e = 0; e < 8; ++e)
        vf[e] = vbase[(size_t)(kv + fq * 8 + e) * RS + db * 16 + fr];
      o[db] = mfma16(pf, vf, o[db]);
    }
    __syncthreads();
  }
#pragma unroll
  for (int r = 0; r < 4; ++r) {
    const int j = j0 + fq * 4 + r;
    if (j < KEEP) {
      const float inv = 1.f / lrow[r];
#pragma unroll
      for (int db = 0; db < 4; ++db)
        out[(rowbase + j) * (size_t)D_ + h * HD_ + db * 16 + fr] =
            (bf16)(o[db][r] * inv);
    }
  }
}

// ----------------------------------------------------------------------------
extern "C" void kernel_launch(void* const* d_in, const int* in_sizes, int n_in,
                              void* d_out, int out_size, void* d_ws, size_t ws_size,
                              hipStream_t stream)
{
  (void)in_sizes; (void)n_in; (void)out_size; (void)ws_size;
  const float* x      = (const float*)d_in[0];
  const float* t_emb  = (const float*)d_in[1];
  const float* tr_w1  = (const float*)d_in[2];
  const float* tr_b1  = (const float*)d_in[3];
  const float* tr_w2  = (const float*)d_in[4];
  const float* tr_b2  = (const float*)d_in[5];
  const float* ln1_w  = (const float*)d_in[6];
  const float* ln1_b  = (const float*)d_in[7];
  const float* ln2_w  = (const float*)d_in[8];
  const float* ln2_b  = (const float*)d_in[9];
  const float* in_w   = (const float*)d_in[10];
  const float* in_b   = (const float*)d_in[11];
  const float* out_w  = (const float*)d_in[12];
  const float* out_b  = (const float*)d_in[13];
  const float* f1_w   = (const float*)d_in[14];
  const float* f1_b   = (const float*)d_in[15];
  const float* f2_w   = (const float*)d_in[16];
  const float* f2_b   = (const float*)d_in[17];
  const float* gate_a = (const float*)d_in[18];
  const float* gate_f = (const float*)d_in[19];

  char* ws = (char*)d_ws;
  size_t off = 0;
  auto alloc = [&](size_t bytes) -> char* {
    char* p = ws + off;
    off = (off + bytes + 255) & ~(size_t)255;
    return p;
  };
  double* imp  = (double*)alloc((size_t)B_ * S_ * 8);
  int* rank    = (int*)alloc((size_t)B_ * S_ * 4);
  int* idx     = (int*)alloc((size_t)B_ * KEEP * 4);
  float* p1    = (float*)alloc((size_t)B_ * 2 * D_ * 4);
  float* p2    = (float*)alloc((size_t)B_ * 2 * D_ * 4);
  bf16* w_in   = (bf16*)alloc((size_t)3 * D_ * D_ * 2);
  bf16* w_out  = (bf16*)alloc((size_t)D_ * D_ * 2);
  bf16* w_f1   = (bf16*)alloc((size_t)DFF_ * D_ * 2);
  bf16* w_f2   = (bf16*)alloc((size_t)D_ * DFF_ * 2);
  bf16* h_bf   = (bf16*)alloc((size_t)MPAD * D_ * 2);
  bf16* big    = (bf16*)alloc((size_t)MPAD * (3 * D_ + D_) * 2);
  bf16* qkv    = big;
  bf16* attn   = big + (size_t)MPAD * 3 * D_;
  bf16* ffn1   = big;   // overlays qkv+attn (both dead by then)

  // d_out starts as a copy of x; gated residuals += into gathered rows.
  hipMemcpyAsync(d_out, x, (size_t)B_ * S_ * D_ * 4, hipMemcpyDeviceToDevice, stream);

  k_importance<<<B_ * S_, 256, 0, stream>>>(x, tr_w1, tr_b1, tr_w2, tr_b2, imp);
  k_rank<<<B_ * 8, 256, 0, stream>>>(imp, rank);
  k_compact<<<B_, 256, 0, stream>>>(rank, idx);

  k_condproj<<<(B_ * 2 * D_) / 4, 256, 0, stream>>>(t_emb, ln1_w, ln1_b, p1);
  k_condproj<<<(B_ * 2 * D_) / 4, 256, 0, stream>>>(t_emb, ln2_w, ln2_b, p2);

  k_f2b<<<(3 * D_ * D_ / 4 + 255) / 256, 256, 0, stream>>>(in_w, w_in, 3 * D_ * D_ / 4);
  k_f2b<<<(D_ * D_ / 4 + 255) / 256, 256, 0, stream>>>(out_w, w_out, D_ * D_ / 4);
  k_f2b<<<(DFF_ * D_ / 4 + 255) / 256, 256, 0, stream>>>(f1_w, w_f1, DFF_ * D_ / 4);
  k_f2b<<<(DFF_ * D_ / 4 + 255) / 256, 256, 0, stream>>>(f2_w, w_f2, DFF_ * D_ / 4);

  k_adaln<<<MPAD, 256, 0, stream>>>(x, idx, p1, h_bf);
  k_gemm<0><<<dim3(3 * D_ / 128, MPAD / 128), 256, 0, stream>>>(
      h_bf, w_in, in_b, qkv, nullptr, nullptr, nullptr, 3 * D_, D_);
  k_attn<<<B_ * H_ * QT, 64, 0, stream>>>(qkv, attn);
  k_gemm<2><<<dim3(D_ / 128, MPAD / 128), 256, 0, stream>>>(
      attn, w_out, out_b, nullptr, gate_a, idx, (float*)d_out, D_, D_);
  k_adaln<<<MPAD, 256, 0, stream>>>((const float*)d_out, idx, p2, h_bf);
  k_gemm<1><<<dim3(DFF_ / 128, MPAD / 128), 256, 0, stream>>>(
      h_bf, w_f1, f1_b, ffn1, nullptr, nullptr, nullptr, DFF_, D_);
  k_gemm<2><<<dim3(D_ / 128, MPAD / 128), 256, 0, stream>>>(
      ffn1, w_f2, f2_b, nullptr, gate_f, idx, (float*)d_out, D_, DFF_);
}

// Round 2
// 638.762 us; speedup vs baseline: 1.2905x; 1.2905x over previous
//
#include <hip/hip_runtime.h>
#include <hip/hip_bf16.h>
#include <cmath>
#include <cstdint>

typedef __bf16 bf16;
typedef __bf16 bf16x8 __attribute__((ext_vector_type(8)));
typedef __bf16 bf16x4 __attribute__((ext_vector_type(4)));
typedef float  f32x4  __attribute__((ext_vector_type(4)));

constexpr int B_   = 4;
constexpr int S_   = 2048;
constexpr int D_   = 1024;
constexpr int H_   = 16;
constexpr int DFF_ = 4096;
constexpr int TD_  = 256;
constexpr int KEEP = 1433;             // int(2048*0.7)
constexpr int M_TOT = B_ * KEEP;       // 5732
constexpr int MPAD  = 5760;            // 45*128
constexpr int QT64  = (KEEP + 63) / 64; // 23
constexpr int NKV   = (KEEP + 63) / 64; // 23
constexpr float EPS = 1e-5f;

__device__ __forceinline__ f32x4 mfma16(bf16x8 a, bf16x8 b, f32x4 c) {
  return __builtin_amdgcn_mfma_f32_16x16x32_bf16(a, b, c, 0, 0, 0);
}

#define GLOAD_LDS(gp, lp)                                                     \
  __builtin_amdgcn_global_load_lds(                                           \
      (const __attribute__((address_space(1))) void*)(gp),                    \
      (__attribute__((address_space(3))) void*)(lp), 16, 0, 0)

// ---------------- token importance (fp64 accumulation for exact ranking) ----
__global__ __launch_bounds__(256) void k_importance(
    const float* __restrict__ x, const float* __restrict__ w1,
    const float* __restrict__ b1, const float* __restrict__ w2,
    const float* __restrict__ b2, double* __restrict__ imp)
{
  const int tok = blockIdx.x;            // b*S + s
  const float* xr = x + (size_t)tok * D_;
  __shared__ float xs[D_];
  __shared__ double part[8][32];
  __shared__ double sacc[32];
  const int t = threadIdx.x;
  for (int i = t; i < D_ / 4; i += 256)
    ((float4*)xs)[i] = ((const float4*)xr)[i];
  __syncthreads();
  const int o = t & 31;       // which of 32 hidden units
  const int ck = t >> 5;      // 0..7 chunk of 128 cols
  const float* wr = w1 + (size_t)o * D_ + ck * 128;
  const float* xc = xs + ck * 128;
  double acc = 0.0;
  for (int c = 0; c < 128; ++c) acc += (double)xc[c] * (double)wr[c];
  part[ck][o] = acc;
  __syncthreads();
  if (t < 32) {
    double s = 0.0;
    for (int c = 0; c < 8; ++c) s += part[c][t];
    s += (double)b1[t];
    double sv = s / (1.0 + exp(-s));    // silu
    sacc[t] = sv * (double)w2[t];
  }
  __syncthreads();
  if (t == 0) {
    double r = 0.0;
    for (int i = 0; i < 32; ++i) r += sacc[i];
    imp[tok] = r + (double)b2[0];
  }
}

// ---------------- rank: #(greater) or (equal && earlier), 4-way split -------
__global__ __launch_bounds__(256) void k_rank(const double* __restrict__ imp,
                                              int* __restrict__ rank)
{
  const int b = blockIdx.x >> 5;
  const int seg = blockIdx.x & 31;     // 64 tokens per block
  __shared__ double vals[S_];
  const double* ib = imp + (size_t)b * S_;
  for (int i = threadIdx.x; i < S_ / 2; i += 256)
    ((double2*)vals)[i] = ((const double2*)ib)[i];
  __syncthreads();
  const int tl = threadIdx.x >> 2;     // token within segment
  const int part = threadIdx.x & 3;    // quarter of the scan
  const int s = seg * 64 + tl;
  const double v = vals[s];
  int cnt = 0;
  for (int j = part * 512; j < (part + 1) * 512; ++j) {
    double u = vals[j];
    cnt += (u > v) || (u == v && j < s);
  }
  cnt += __shfl_xor(cnt, 1);
  cnt += __shfl_xor(cnt, 2);
  if (part == 0) rank[b * S_ + s] = cnt;
}

// ---------------- compact kept indices (ascending) ---------------------------
__global__ __launch_bounds__(256) void k_compact(const int* __restrict__ rank,
                                                 int* __restrict__ idx)
{
  const int b = blockIdx.x;
  __shared__ int wcnt[4];
  __shared__ int base_s;
  if (threadIdx.x == 0) base_s = 0;
  __syncthreads();
  const int t = threadIdx.x, lane = t & 63, w = t >> 6;
  for (int c = 0; c < S_ / 256; ++c) {
    const int s = c * 256 + t;
    const bool kept = rank[b * S_ + s] < KEEP;
    unsigned long long m = __ballot(kept);
    int piw = __popcll(m & ((1ull << lane) - 1ull));
    if (lane == 0) wcnt[w] = __popcll(m);
    __syncthreads();
    int off = base_s;
    for (int i = 0; i < w; ++i) off += wcnt[i];
    if (kept) idx[b * KEEP + off + piw] = s;
    __syncthreads();
    if (t == 0) base_s += wcnt[0] + wcnt[1] + wcnt[2] + wcnt[3];
    __syncthreads();
  }
}

// ---------------- cond projection: p = silu(t_emb) @ W.T + b ----------------
__global__ __launch_bounds__(256) void k_condproj(
    const float* __restrict__ temb, const float* __restrict__ W,
    const float* __restrict__ bias, float* __restrict__ p)
{
  const int gw = (int)((blockIdx.x * 256 + threadIdx.x) >> 6);
  const int lane = threadIdx.x & 63;
  const int b = gw >> 11;          // 2048 outputs per batch
  const int row = gw & 2047;
  const float* te = temb + (size_t)b * TD_;
  const float* wr = W + (size_t)row * TD_;
  float acc = 0.f;
  for (int i = lane; i < TD_; i += 64) {
    float c = te[i];
    acc += (c / (1.f + __expf(-c))) * wr[i];
  }
  for (int o = 32; o > 0; o >>= 1) acc += __shfl_down(acc, o);
  if (lane == 0) p[(size_t)b * 2 * D_ + row] = acc + bias[row];
}

// ---------------- fp32 -> bf16 weight cast ----------------------------------
__global__ void k_f2b(const float* __restrict__ src, bf16* __restrict__ dst, int n4)
{
  int i = blockIdx.x * 256 + threadIdx.x;
  if (i < n4) {
    float4 v = ((const float4*)src)[i];
    bf16x4 o = {(bf16)v.x, (bf16)v.y, (bf16)v.z, (bf16)v.w};
    ((bf16x4*)dst)[i] = o;
  }
}

// ---------------- gather + adaLN -> bf16 -------------------------------------
__global__ __launch_bounds__(256) void k_adaln(
    const float* __restrict__ xsrc, const int* __restrict__ idx,
    const float* __restrict__ p, bf16* __restrict__ hout)
{
  const int r = blockIdx.x, t = threadIdx.x;
  bf16* orow = hout + (size_t)r * D_;
  if (r >= M_TOT) {
    bf16x4 z = {(bf16)0.f, (bf16)0.f, (bf16)0.f, (bf16)0.f};
    ((bf16x4*)orow)[t] = z;
    return;
  }
  const int b = r / KEEP, j = r - b * KEEP;
  const int s = idx[b * KEEP + j];
  const float* xr = xsrc + ((size_t)(b * S_ + s)) * D_;
  float4 v = ((const float4*)xr)[t];
  __shared__ float red[8];
  float sum = v.x + v.y + v.z + v.w;
  for (int o = 32; o > 0; o >>= 1) sum += __shfl_down(sum, o);
  const int lane = t & 63, w = t >> 6;
  if (lane == 0) red[w] = sum;
  __syncthreads();
  const float mu = (red[0] + red[1] + red[2] + red[3]) * (1.f / D_);
  const float dx = v.x - mu, dy = v.y - mu, dz = v.z - mu, dw = v.w - mu;
  float vs = dx * dx + dy * dy + dz * dz + dw * dw;
  for (int o = 32; o > 0; o >>= 1) vs += __shfl_down(vs, o);
  if (lane == 0) red[4 + w] = vs;
  __syncthreads();
  const float rstd = rsqrtf((red[4] + red[5] + red[6] + red[7]) * (1.f / D_) + EPS);
  const float* gp = p + (size_t)b * 2 * D_;
  float4 g  = ((const float4*)gp)[t];
  float4 be = ((const float4*)(gp + D_))[t];
  bf16x4 o;
  o[0] = (bf16)(dx * rstd * (1.f + g.x) + be.x);
  o[1] = (bf16)(dy * rstd * (1.f + g.y) + be.y);
  o[2] = (bf16)(dz * rstd * (1.f + g.z) + be.z);
  o[3] = (bf16)(dw * rstd * (1.f + g.w) + be.w);
  ((bf16x4*)orow)[t] = o;
}

// ---------------- GEMM: C[m][n] = sum_k A[m][k] * W[n][k]  (+ epilogues) -----
template <int MODE>
__global__ __launch_bounds__(256) void k_gemm(
    const bf16* __restrict__ A, const bf16* __restrict__ W,
    const float* __restrict__ bias, bf16* __restrict__ Cbf,
    const float* __restrict__ gate, const int* __restrict__ idx,
    float* __restrict__ resid, int N, int K)
{
  __shared__ bf16 As[128 * 32];
  __shared__ bf16 Ws[128 * 32];
  const int t = threadIdx.x, lane = t & 63;
  const int w = t >> 6, wr = w >> 1, wc = w & 1;
  const int fr = lane & 15, fq = lane >> 4;
  const int bm = blockIdx.y, bn = blockIdx.x;
  const bf16* Ab = A + (size_t)bm * 128 * K;
  const bf16* Wb = W + (size_t)bn * 128 * K;
  f32x4 acc[4][4] = {};
  for (int kt = 0; kt < K; kt += 32) {
#pragma unroll
    for (int it = 0; it < 2; ++it) {
      int e = it * 256 + t;
      int row = e >> 2, c = e & 3;
      GLOAD_LDS(Ab + (size_t)row * K + kt + c * 8, As + (size_t)e * 8);
      GLOAD_LDS(Wb + (size_t)row * K + kt + c * 8, Ws + (size_t)e * 8);
    }
    __syncthreads();
    bf16x8 af[4], wf[4];
#pragma unroll
    for (int i = 0; i < 4; ++i) {
      af[i] = *(const bf16x8*)(As + (wr * 64 + i * 16 + fr) * 32 + fq * 8);
      wf[i] = *(const bf16x8*)(Ws + (wc * 64 + i * 16 + fr) * 32 + fq * 8);
    }
#pragma unroll
    for (int i = 0; i < 4; ++i)
#pragma unroll
      for (int j = 0; j < 4; ++j)
        acc[i][j] = mfma16(af[i], wf[j], acc[i][j]);
    __syncthreads();
  }
#pragma unroll
  for (int i = 0; i < 4; ++i) {
#pragma unroll
    for (int j = 0; j < 4; ++j) {
#pragma unroll
      for (int r = 0; r < 4; ++r) {
        const int m = bm * 128 + wr * 64 + i * 16 + fq * 4 + r;
        const int n = bn * 128 + wc * 64 + j * 16 + fr;
        float v = acc[i][j][r] + bias[n];
        if (MODE == 0) {
          Cbf[(size_t)m * N + n] = (bf16)v;
        } else if (MODE == 1) {
          float gl = 0.5f * v * (1.f + erff(v * 0.70710678118654752f));
          Cbf[(size_t)m * N + n] = (bf16)gl;
        } else {
          if (m < M_TOT) {
            const int b = m / KEEP, jj = m - b * KEEP;
            const int s = idx[b * KEEP + jj];
            resid[((size_t)(b * S_ + s)) * D_ + n] += gate[n] * v;
          }
        }
      }
    }
  }
}

// ---------------- flash attention: 4 waves/block, 64 q-rows, KV tile 64 ------
// K staged XOR-swizzled (G4 fix); V staged into tr-read subtile layout via
// pre-swizzled global source; PV B-fragments via ds_read_b64_tr_b16;
// 2-phase double-buffered staging (T3 minimum recipe).
__global__ __launch_bounds__(256) void k_attn(const bf16* __restrict__ qkv,
                                              bf16* __restrict__ out)
{
  __shared__ bf16 Klds[2][64 * 64];
  __shared__ bf16 Vlds[2][64 * 64];
  __shared__ bf16 plds[4][16 * 64];

  const int t = threadIdx.x;
  const int lane = t & 63, w = t >> 6;
  const int fr = lane & 15, fq = lane >> 4;
  const int qt = blockIdx.x, h = blockIdx.y, b = blockIdx.z;
  const size_t rowbase = (size_t)b * KEEP;
  const size_t RS = 3 * D_;
  const bf16* kbase = qkv + rowbase * RS + D_ + h * 64;
  const bf16* vbase = qkv + rowbase * RS + 2 * D_ + h * 64;

  // Q fragments (A-operand rows = fr)
  const int wq0 = qt * 64 + w * 16;
  {
  }
  const int qrow = min(wq0 + fr, KEEP - 1);
  const bf16* qp = qkv + (rowbase + qrow) * RS + h * 64 + fq * 8;
  const bf16x8 qf0 = *(const bf16x8*)qp;
  const bf16x8 qf1 = *(const bf16x8*)(qp + 32);

  f32x4 o[4] = {};
  float mrow[4] = {-INFINITY, -INFINITY, -INFINITY, -INFINITY};
  float lrow[4] = {0.f, 0.f, 0.f, 0.f};

  // stage tile `kv` into buffer `buf`
  auto stage = [&](int buf, int kv) {
#pragma unroll
    for (int rnd = 0; rnd < 2; ++rnd) {
      const int p = rnd * 256 + t;
      // K: row-major [64][64], chunk XOR-swizzled by row&7
      {
        const int row = p >> 3, c8p = p & 7;
        const int c8 = c8p ^ (row & 7);
        const int gr = min(kv + row, KEEP - 1);
        GLOAD_LDS(kbase + (size_t)gr * RS + c8 * 8, &Klds[buf][0] + p * 8);
      }
      // V: subtiled [db][ksub][4][16] for tr-read
      {
        const int db = p >> 7, ksub = (p >> 3) & 15, jr = (p >> 1) & 3,
                  c8lo = p & 1;
        const int vrow = ksub * 4 + jr, vc8 = db * 2 + c8lo;
        const int gr = min(kv + vrow, KEEP - 1);
        GLOAD_LDS(vbase + (size_t)gr * RS + vc8 * 8, &Vlds[buf][0] + p * 8);
      }
    }
  };

  stage(0, 0);
  int cur = 0;

  char* pw = (char*)&plds[w][0];
  const unsigned vbase_lds0 =
      (unsigned)(size_t)(__attribute__((address_space(3))) bf16*)&Vlds[0][0];
  const unsigned vbase_lds1 =
      (unsigned)(size_t)(__attribute__((address_space(3))) bf16*)&Vlds[1][0];

  for (int ti = 0; ti < NKV; ++ti) {
    const int kv = ti * 64;
    __syncthreads();                       // stage(cur) complete; prev compute done
    if (ti + 1 < NKV) stage(cur ^ 1, kv + 64);

    const char* Kl = (const char*)&Klds[cur][0];

    // ---- QK^T: S[16q][64k] in 4 fragments
    f32x4 sc[4];
#pragma unroll
    for (int kb = 0; kb < 4; ++kb) {
      const int row = kb * 16 + fr;
      const bf16x8 kf0 =
          *(const bf16x8*)(Kl + row * 128 + ((fq ^ (row & 7)) << 4));
      const bf16x8 kf1 =
          *(const bf16x8*)(Kl + row * 128 + (((4 + fq) ^ (row & 7)) << 4));
      f32x4 s = {0.f, 0.f, 0.f, 0.f};
      s = mfma16(qf0, kf0, s);
      s = mfma16(qf1, kf1, s);
      sc[kb] = s;
    }

    // ---- online softmax (rows q = fq*4+r), P -> swizzled per-wave LDS
    float fac[4];
#pragma unroll
    for (int r = 0; r < 4; ++r) {
      const int q = fq * 4 + r;
      float s[4];
#pragma unroll
      for (int kb = 0; kb < 4; ++kb) {
        const bool valid = (kv + kb * 16 + fr) < KEEP;
        s[kb] = valid ? sc[kb][r] * 0.125f : -INFINITY;
      }
      float mx = fmaxf(fmaxf(s[0], s[1]), fmaxf(s[2], s[3]));
      mx = fmaxf(mx, __shfl_xor(mx, 1));
      mx = fmaxf(mx, __shfl_xor(mx, 2));
      mx = fmaxf(mx, __shfl_xor(mx, 4));
      mx = fmaxf(mx, __shfl_xor(mx, 8));
      const float mnew = fmaxf(mrow[r], mx);
      float ps = 0.f;
#pragma unroll
      for (int kb = 0; kb < 4; ++kb) {
        const float pv = __expf(s[kb] - mnew);
        ps += pv;
        const int chunk = kb * 2 + (fr >> 3);
        *(bf16*)(pw + q * 128 + ((chunk ^ (q & 7)) << 4) + (fr & 7) * 2) =
            (bf16)pv;
      }
      ps += __shfl_xor(ps, 1);
      ps += __shfl_xor(ps, 2);
      ps += __shfl_xor(ps, 4);
      ps += __shfl_xor(ps, 8);
      const float f = __expf(mrow[r] - mnew);
      lrow[r] = lrow[r] * f + ps;
      mrow[r] = mnew;
      fac[r] = f;
    }
#pragma unroll
    for (int db = 0; db < 4; ++db) {
      o[db][0] *= fac[0]; o[db][1] *= fac[1];
      o[db][2] *= fac[2]; o[db][3] *= fac[3];
    }

    // ---- PV: O[16q][64d] += P[16][64] * V[64][64]
    const unsigned vb =
        (cur ? vbase_lds1 : vbase_lds0) + ((unsigned)(lane >> 4) << 7);
#pragma unroll
    for (int kb32 = 0; kb32 < 2; ++kb32) {
      const bf16x8 pa = *(const bf16x8*)(
          pw + fr * 128 + (((kb32 * 4 + fq) ^ (fr & 7)) << 4));
      const unsigned addr = vb + kb32 * 1024;
      bf16x4 t0, t1, t2, t3, t4, t5, t6, t7;
      asm volatile(
          "ds_read_b64_tr_b16 %0, %8 offset:0\n\t"
          "ds_read_b64_tr_b16 %1, %8 offset:128\n\t"
          "ds_read_b64_tr_b16 %2, %8 offset:2048\n\t"
          "ds_read_b64_tr_b16 %3, %8 offset:2176\n\t"
          "ds_read_b64_tr_b16 %4, %8 offset:4096\n\t"
          "ds_read_b64_tr_b16 %5, %8 offset:4224\n\t"
          "ds_read_b64_tr_b16 %6, %8 offset:6144\n\t"
          "ds_read_b64_tr_b16 %7, %8 offset:6272\n\t"
          "s_waitcnt lgkmcnt(0)"
          : "=&v"(t0), "=&v"(t1), "=&v"(t2), "=&v"(t3),
            "=&v"(t4), "=&v"(t5), "=&v"(t6), "=&v"(t7)
          : "v"(addr));
      const bf16x8 vf0 = __builtin_shufflevector(t0, t1, 0, 1, 2, 3, 4, 5, 6, 7);
      const bf16x8 vf1 = __builtin_shufflevector(t2, t3, 0, 1, 2, 3, 4, 5, 6, 7);
      const bf16x8 vf2 = __builtin_shufflevector(t4, t5, 0, 1, 2, 3, 4, 5, 6, 7);
      const bf16x8 vf3 = __builtin_shufflevector(t6, t7, 0, 1, 2, 3, 4, 5, 6, 7);
      o[0] = mfma16(pa, vf0, o[0]);
      o[1] = mfma16(pa, vf1, o[1]);
      o[2] = mfma16(pa, vf2, o[2]);
      o[3] = mfma16(pa, vf3, o[3]);
    }
    cur ^= 1;
  }

  // ---- epilogue
#pragma unroll
  for (int r = 0; r < 4; ++r) {
    const int q = wq0 + fq * 4 + r;
    if (q < KEEP) {
      const float inv = 1.f / lrow[r];
#pragma unroll
      for (int db = 0; db < 4; ++db)
        out[(rowbase + q) * (size_t)D_ + h * 64 + db * 16 + fr] =
            (bf16)(o[db][r] * inv);
    }
  }
}

// ----------------------------------------------------------------------------
extern "C" void kernel_launch(void* const* d_in, const int* in_sizes, int n_in,
                              void* d_out, int out_size, void* d_ws, size_t ws_size,
                              hipStream_t stream)
{
  (void)in_sizes; (void)n_in; (void)out_size; (void)ws_size;
  const float* x      = (const float*)d_in[0];
  const float* t_emb  = (const float*)d_in[1];
  const float* tr_w1  = (const float*)d_in[2];
  const float* tr_b1  = (const float*)d_in[3];
  const float* tr_w2  = (const float*)d_in[4];
  const float* tr_b2  = (const float*)d_in[5];
  const float* ln1_w  = (const float*)d_in[6];
  const float* ln1_b  = (const float*)d_in[7];
  const float* ln2_w  = (const float*)d_in[8];
  const float* ln2_b  = (const float*)d_in[9];
  const float* in_w   = (const float*)d_in[10];
  const float* in_b   = (const float*)d_in[11];
  const float* out_w  = (const float*)d_in[12];
  const float* out_b  = (const float*)d_in[13];
  const float* f1_w   = (const float*)d_in[14];
  const float* f1_b   = (const float*)d_in[15];
  const float* f2_w   = (const float*)d_in[16];
  const float* f2_b   = (const float*)d_in[17];
  const float* gate_a = (const float*)d_in[18];
  const float* gate_f = (const float*)d_in[19];

  char* ws = (char*)d_ws;
  size_t off = 0;
  auto alloc = [&](size_t bytes) -> char* {
    char* p = ws + off;
    off = (off + bytes + 255) & ~(size_t)255;
    return p;
  };
  double* imp  = (double*)alloc((size_t)B_ * S_ * 8);
  int* rank    = (int*)alloc((size_t)B_ * S_ * 4);
  int* idx     = (int*)alloc((size_t)B_ * KEEP * 4);
  float* p1    = (float*)alloc((size_t)B_ * 2 * D_ * 4);
  float* p2    = (float*)alloc((size_t)B_ * 2 * D_ * 4);
  bf16* w_in   = (bf16*)alloc((size_t)3 * D_ * D_ * 2);
  bf16* w_out  = (bf16*)alloc((size_t)D_ * D_ * 2);
  bf16* w_f1   = (bf16*)alloc((size_t)DFF_ * D_ * 2);
  bf16* w_f2   = (bf16*)alloc((size_t)D_ * DFF_ * 2);
  bf16* h_bf   = (bf16*)alloc((size_t)MPAD * D_ * 2);
  bf16* big    = (bf16*)alloc((size_t)MPAD * (3 * D_ + D_) * 2);
  bf16* qkv    = big;
  bf16* attn   = big + (size_t)MPAD * 3 * D_;
  bf16* ffn1   = big;   // overlays qkv+attn (both dead by then)

  hipMemcpyAsync(d_out, x, (size_t)B_ * S_ * D_ * 4, hipMemcpyDeviceToDevice, stream);

  k_importance<<<B_ * S_, 256, 0, stream>>>(x, tr_w1, tr_b1, tr_w2, tr_b2, imp);
  k_rank<<<B_ * 32, 256, 0, stream>>>(imp, rank);
  k_compact<<<B_, 256, 0, stream>>>(rank, idx);

  k_condproj<<<(B_ * 2 * D_) / 4, 256, 0, stream>>>(t_emb, ln1_w, ln1_b, p1);
  k_condproj<<<(B_ * 2 * D_) / 4, 256, 0, stream>>>(t_emb, ln2_w, ln2_b, p2);

  k_f2b<<<(3 * D_ * D_ / 4 + 255) / 256, 256, 0, stream>>>(in_w, w_in, 3 * D_ * D_ / 4);
  k_f2b<<<(D_ * D_ / 4 + 255) / 256, 256, 0, stream>>>(out_w, w_out, D_ * D_ / 4);
  k_f2b<<<(DFF_ * D_ / 4 + 255) / 256, 256, 0, stream>>>(f1_w, w_f1, DFF_ * D_ / 4);
  k_f2b<<<(DFF_ * D_ / 4 + 255) / 256, 256, 0, stream>>>(f2_w, w_f2, DFF_ * D_ / 4);

  k_adaln<<<MPAD, 256, 0, stream>>>(x, idx, p1, h_bf);
  k_gemm<0><<<dim3(3 * D_ / 128, MPAD / 128), 256, 0, stream>>>(
      h_bf, w_in, in_b, qkv, nullptr, nullptr, nullptr, 3 * D_, D_);
  k_attn<<<dim3(QT64, H_, B_), 256, 0, stream>>>(qkv, attn);
  k_gemm<2><<<dim3(D_ / 128, MPAD / 128), 256, 0, stream>>>(
      attn, w_out, out_b, nullptr, gate_a, idx, (float*)d_out, D_, D_);
  k_adaln<<<MPAD, 256, 0, stream>>>((const float*)d_out, idx, p2, h_bf);
  k_gemm<1><<<dim3(DFF_ / 128, MPAD / 128), 256, 0, stream>>>(
      h_bf, w_f1, f1_b, ffn1, nullptr, nullptr, nullptr, DFF_, D_);
  k_gemm<2><<<dim3(D_ / 128, MPAD / 128), 256, 0, stream>>>(
      ffn1, w_f2, f2_b, nullptr, gate_f, idx, (float*)d_out, D_, DFF_);
}

// Round 3
// 556.845 us; speedup vs baseline: 1.4804x; 1.1471x over previous
//
#include <hip/hip_runtime.h>
#include <hip/hip_bf16.h>
#include <cmath>
#include <cstdint>

typedef __bf16 bf16;
typedef __bf16 bf16x8 __attribute__((ext_vector_type(8)));
typedef __bf16 bf16x4 __attribute__((ext_vector_type(4)));
typedef float  f32x4  __attribute__((ext_vector_type(4)));

constexpr int B_   = 4;
constexpr int S_   = 2048;
constexpr int D_   = 1024;
constexpr int H_   = 16;
constexpr int DFF_ = 4096;
constexpr int TD_  = 256;
constexpr int KEEP = 1433;             // int(2048*0.7)
constexpr int M_TOT = B_ * KEEP;       // 5732
constexpr int MPAD  = 5760;            // 45*128
constexpr int QT64  = (KEEP + 63) / 64; // 23
constexpr int NKV   = (KEEP + 63) / 64; // 23
constexpr float EPS = 1e-5f;

__device__ __forceinline__ f32x4 mfma16(bf16x8 a, bf16x8 b, f32x4 c) {
  return __builtin_amdgcn_mfma_f32_16x16x32_bf16(a, b, c, 0, 0, 0);
}

#define GLOAD_LDS(gp, lp)                                                     \
  __builtin_amdgcn_global_load_lds(                                           \
      (const __attribute__((address_space(1))) void*)(gp),                    \
      (__attribute__((address_space(3))) void*)(lp), 16, 0, 0)

// ---------------- token importance (fp64 accumulation for exact ranking) ----
__global__ __launch_bounds__(256) void k_importance(
    const float* __restrict__ x, const float* __restrict__ w1,
    const float* __restrict__ b1, const float* __restrict__ w2,
    const float* __restrict__ b2, double* __restrict__ imp)
{
  const int tok = blockIdx.x;            // b*S + s
  const float* xr = x + (size_t)tok * D_;
  __shared__ float xs[D_];
  __shared__ double part[8][32];
  __shared__ double sacc[32];
  const int t = threadIdx.x;
  for (int i = t; i < D_ / 4; i += 256)
    ((float4*)xs)[i] = ((const float4*)xr)[i];
  __syncthreads();
  const int o = t & 31;       // which of 32 hidden units
  const int ck = t >> 5;      // 0..7 chunk of 128 cols
  const float* wr = w1 + (size_t)o * D_ + ck * 128;
  const float* xc = xs + ck * 128;
  double acc = 0.0;
  for (int c = 0; c < 128; ++c) acc += (double)xc[c] * (double)wr[c];
  part[ck][o] = acc;
  __syncthreads();
  if (t < 32) {
    double s = 0.0;
    for (int c = 0; c < 8; ++c) s += part[c][t];
    s += (double)b1[t];
    double sv = s / (1.0 + exp(-s));    // silu
    sacc[t] = sv * (double)w2[t];
  }
  __syncthreads();
  if (t == 0) {
    double r = 0.0;
    for (int i = 0; i < 32; ++i) r += sacc[i];
    imp[tok] = r + (double)b2[0];
  }
}

// ---------------- rank: #(greater) or (equal && earlier) ---------------------
__global__ __launch_bounds__(256) void k_rank(const double* __restrict__ imp,
                                              int* __restrict__ rank)
{
  const int b = blockIdx.x >> 5;
  const int seg = blockIdx.x & 31;     // 64 tokens per block
  __shared__ double vals[S_];
  const double* ib = imp + (size_t)b * S_;
  for (int i = threadIdx.x; i < S_ / 2; i += 256)
    ((double2*)vals)[i] = ((const double2*)ib)[i];
  __syncthreads();
  const int tl = threadIdx.x >> 2;     // token within segment
  const int part = threadIdx.x & 3;    // quarter of the scan
  const int s = seg * 64 + tl;
  const double v = vals[s];
  int cnt = 0;
  for (int j = part * 512; j < (part + 1) * 512; ++j) {
    double u = vals[j];
    cnt += (u > v) || (u == v && j < s);
  }
  cnt += __shfl_xor(cnt, 1);
  cnt += __shfl_xor(cnt, 2);
  if (part == 0) rank[b * S_ + s] = cnt;
}

// ---------------- compact kept indices (ascending) ---------------------------
__global__ __launch_bounds__(256) void k_compact(const int* __restrict__ rank,
                                                 int* __restrict__ idx)
{
  const int b = blockIdx.x;
  __shared__ int wcnt[4];
  __shared__ int base_s;
  if (threadIdx.x == 0) base_s = 0;
  __syncthreads();
  const int t = threadIdx.x, lane = t & 63, w = t >> 6;
  for (int c = 0; c < S_ / 256; ++c) {
    const int s = c * 256 + t;
    const bool kept = rank[b * S_ + s] < KEEP;
    unsigned long long m = __ballot(kept);
    int piw = __popcll(m & ((1ull << lane) - 1ull));
    if (lane == 0) wcnt[w] = __popcll(m);
    __syncthreads();
    int off = base_s;
    for (int i = 0; i < w; ++i) off += wcnt[i];
    if (kept) idx[b * KEEP + off + piw] = s;
    __syncthreads();
    if (t == 0) base_s += wcnt[0] + wcnt[1] + wcnt[2] + wcnt[3];
    __syncthreads();
  }
}

// ---------------- cond projection: p = silu(t_emb) @ W.T + b ----------------
__global__ __launch_bounds__(256) void k_condproj(
    const float* __restrict__ temb, const float* __restrict__ W,
    const float* __restrict__ bias, float* __restrict__ p)
{
  const int gw = (int)((blockIdx.x * 256 + threadIdx.x) >> 6);
  const int lane = threadIdx.x & 63;
  const int b = gw >> 11;          // 2048 outputs per batch
  const int row = gw & 2047;
  const float* te = temb + (size_t)b * TD_;
  const float* wr = W + (size_t)row * TD_;
  float acc = 0.f;
  for (int i = lane; i < TD_; i += 64) {
    float c = te[i];
    acc += (c / (1.f + __expf(-c))) * wr[i];
  }
  for (int o = 32; o > 0; o >>= 1) acc += __shfl_down(acc, o);
  if (lane == 0) p[(size_t)b * 2 * D_ + row] = acc + bias[row];
}

// ---------------- fp32 -> bf16 weight cast ----------------------------------
__global__ void k_f2b(const float* __restrict__ src, bf16* __restrict__ dst, int n4)
{
  int i = blockIdx.x * 256 + threadIdx.x;
  if (i < n4) {
    float4 v = ((const float4*)src)[i];
    bf16x4 o = {(bf16)v.x, (bf16)v.y, (bf16)v.z, (bf16)v.w};
    ((bf16x4*)dst)[i] = o;
  }
}

// ---------------- gather + adaLN -> bf16 -------------------------------------
__global__ __launch_bounds__(256) void k_adaln(
    const float* __restrict__ xsrc, const int* __restrict__ idx,
    const float* __restrict__ p, bf16* __restrict__ hout)
{
  const int r = blockIdx.x, t = threadIdx.x;
  bf16* orow = hout + (size_t)r * D_;
  if (r >= M_TOT) {
    bf16x4 z = {(bf16)0.f, (bf16)0.f, (bf16)0.f, (bf16)0.f};
    ((bf16x4*)orow)[t] = z;
    return;
  }
  const int b = r / KEEP, j = r - b * KEEP;
  const int s = idx[b * KEEP + j];
  const float* xr = xsrc + ((size_t)(b * S_ + s)) * D_;
  float4 v = ((const float4*)xr)[t];
  __shared__ float red[8];
  float sum = v.x + v.y + v.z + v.w;
  for (int o = 32; o > 0; o >>= 1) sum += __shfl_down(sum, o);
  const int lane = t & 63, w = t >> 6;
  if (lane == 0) red[w] = sum;
  __syncthreads();
  const float mu = (red[0] + red[1] + red[2] + red[3]) * (1.f / D_);
  const float dx = v.x - mu, dy = v.y - mu, dz = v.z - mu, dw = v.w - mu;
  float vs = dx * dx + dy * dy + dz * dz + dw * dw;
  for (int o = 32; o > 0; o >>= 1) vs += __shfl_down(vs, o);
  if (lane == 0) red[4 + w] = vs;
  __syncthreads();
  const float rstd = rsqrtf((red[4] + red[5] + red[6] + red[7]) * (1.f / D_) + EPS);
  const float* gp = p + (size_t)b * 2 * D_;
  float4 g  = ((const float4*)gp)[t];
  float4 be = ((const float4*)(gp + D_))[t];
  bf16x4 o;
  o[0] = (bf16)(dx * rstd * (1.f + g.x) + be.x);
  o[1] = (bf16)(dy * rstd * (1.f + g.y) + be.y);
  o[2] = (bf16)(dz * rstd * (1.f + g.z) + be.z);
  o[3] = (bf16)(dw * rstd * (1.f + g.w) + be.w);
  ((bf16x4*)orow)[t] = o;
}

// ---------------- GEMM: C[m][n] = sum_k A[m][k] * W[n][k]  (+ epilogues) -----
// BK=64, XOR-swizzled LDS (T2, via pre-swizzled gload source), double-buffered
// 2-phase schedule (T3 minimum), bijective XCD swizzle (T1).
// MODE 0: bias -> bf16. MODE 1: bias+gelu -> bf16.
// MODE 2: bias, then resid[row(m)][n] += gate[n]*v (gathered residual).
template <int BN, int MODE>
__global__ __launch_bounds__(256) void k_gemm(
    const bf16* __restrict__ A, const bf16* __restrict__ W,
    const float* __restrict__ bias, bf16* __restrict__ Cbf,
    const float* __restrict__ gate, const int* __restrict__ idx,
    float* __restrict__ resid, int N, int K, int gn)
{
  constexpr int WN = BN / 2;      // per-wave N span
  constexpr int NJ = WN / 16;     // N fragments per wave
  __shared__ bf16 As[2][128 * 64];
  __shared__ bf16 Ws[2][BN * 64];
  const int t = threadIdx.x, lane = t & 63;
  const int w = t >> 6, wr = w >> 1, wc = w & 1;
  const int fr = lane & 15, fq = lane >> 4;

  // bijective XCD-contiguous remap (m204)
  const int nwg = gridDim.x, orig = blockIdx.x;
  const int q8 = nwg >> 3, r8 = nwg & 7;
  const int xc = orig & 7, pos = orig >> 3;
  const int wgid = (xc < r8 ? xc * (q8 + 1) : r8 * (q8 + 1) + (xc - r8) * q8) + pos;
  const int bm = wgid / gn, bn = wgid - bm * gn;

  const bf16* Ab = A + (size_t)bm * 128 * K;
  const bf16* Wb = W + (size_t)bn * BN * K;

  auto stage = [&](int buf, int kt) {
    const int ko = kt * 64;
#pragma unroll
    for (int it = 0; it < 4; ++it) {
      const int e = it * 256 + t;
      const int row = e >> 3, pc = e & 7;
      const int lc = pc ^ (row & 7);
      GLOAD_LDS(Ab + (size_t)row * K + ko + lc * 8, &As[buf][0] + e * 8);
    }
#pragma unroll
    for (int it = 0; it < BN / 32; ++it) {
      const int e = it * 256 + t;
      const int row = e >> 3, pc = e & 7;
      const int lc = pc ^ (row & 7);
      GLOAD_LDS(Wb + (size_t)row * K + ko + lc * 8, &Ws[buf][0] + e * 8);
    }
  };

  f32x4 acc[4][NJ] = {};
  stage(0, 0);
  const int nkt = K >> 6;
  int cur = 0;
  for (int kt = 0; kt < nkt; ++kt) {
    __syncthreads();                   // stage(cur) landed; prev reads done
    if (kt + 1 < nkt) stage(cur ^ 1, kt + 1);
    const char* Al = (const char*)&As[cur][0];
    const char* Wl = (const char*)&Ws[cur][0];
#pragma unroll
    for (int kk = 0; kk < 2; ++kk) {
      bf16x8 af[4], wf[NJ];
#pragma unroll
      for (int i = 0; i < 4; ++i)
        af[i] = *(const bf16x8*)(Al + (wr * 64 + i * 16 + fr) * 128 +
                                 (((kk * 4 + fq) ^ (fr & 7)) << 4));
#pragma unroll
      for (int j = 0; j < NJ; ++j)
        wf[j] = *(const bf16x8*)(Wl + (wc * WN + j * 16 + fr) * 128 +
                                 (((kk * 4 + fq) ^ (fr & 7)) << 4));
#pragma unroll
      for (int i = 0; i < 4; ++i)
#pragma unroll
        for (int j = 0; j < NJ; ++j)
          acc[i][j] = mfma16(af[i], wf[j], acc[i][j]);
    }
    cur ^= 1;
  }

#pragma unroll
  for (int i = 0; i < 4; ++i) {
#pragma unroll
    for (int j = 0; j < NJ; ++j) {
#pragma unroll
      for (int r = 0; r < 4; ++r) {
        const int m = bm * 128 + wr * 64 + i * 16 + fq * 4 + r;
        const int n = bn * BN + wc * WN + j * 16 + fr;
        float v = acc[i][j][r] + bias[n];
        if (MODE == 0) {
          Cbf[(size_t)m * N + n] = (bf16)v;
        } else if (MODE == 1) {
          float gl = 0.5f * v * (1.f + erff(v * 0.70710678118654752f));
          Cbf[(size_t)m * N + n] = (bf16)gl;
        } else {
          if (m < M_TOT) {
            const int b = m / KEEP, jj = m - b * KEEP;
            const int s = idx[b * KEEP + jj];
            resid[((size_t)(b * S_ + s)) * D_ + n] += gate[n] * v;
          }
        }
      }
    }
  }
}

// ---------------- flash attention: 4 waves/block, 64 q-rows, KV tile 64 ------
__global__ __launch_bounds__(256) void k_attn(const bf16* __restrict__ qkv,
                                              bf16* __restrict__ out)
{
  __shared__ bf16 Klds[2][64 * 64];
  __shared__ bf16 Vlds[2][64 * 64];
  __shared__ bf16 plds[4][16 * 64];

  const int t = threadIdx.x;
  const int lane = t & 63, w = t >> 6;
  const int fr = lane & 15, fq = lane >> 4;
  const int qt = blockIdx.x, h = blockIdx.y, b = blockIdx.z;
  const size_t rowbase = (size_t)b * KEEP;
  const size_t RS = 3 * D_;
  const bf16* kbase = qkv + rowbase * RS + D_ + h * 64;
  const bf16* vbase = qkv + rowbase * RS + 2 * D_ + h * 64;

  const int wq0 = qt * 64 + w * 16;
  const int qrow = min(wq0 + fr, KEEP - 1);
  const bf16* qp = qkv + (rowbase + qrow) * RS + h * 64 + fq * 8;
  const bf16x8 qf0 = *(const bf16x8*)qp;
  const bf16x8 qf1 = *(const bf16x8*)(qp + 32);

  f32x4 o[4] = {};
  float mrow[4] = {-INFINITY, -INFINITY, -INFINITY, -INFINITY};
  float lrow[4] = {0.f, 0.f, 0.f, 0.f};

  auto stage = [&](int buf, int kv) {
#pragma unroll
    for (int rnd = 0; rnd < 2; ++rnd) {
      const int p = rnd * 256 + t;
      {
        const int row = p >> 3, c8p = p & 7;
        const int c8 = c8p ^ (row & 7);
        const int gr = min(kv + row, KEEP - 1);
        GLOAD_LDS(kbase + (size_t)gr * RS + c8 * 8, &Klds[buf][0] + p * 8);
      }
      {
        const int db = p >> 7, ksub = (p >> 3) & 15, jr = (p >> 1) & 3,
                  c8lo = p & 1;
        const int vrow = ksub * 4 + jr, vc8 = db * 2 + c8lo;
        const int gr = min(kv + vrow, KEEP - 1);
        GLOAD_LDS(vbase + (size_t)gr * RS + vc8 * 8, &Vlds[buf][0] + p * 8);
      }
    }
  };

  stage(0, 0);
  int cur = 0;

  char* pw = (char*)&plds[w][0];
  const unsigned vbase_lds0 =
      (unsigned)(size_t)(__attribute__((address_space(3))) bf16*)&Vlds[0][0];
  const unsigned vbase_lds1 =
      (unsigned)(size_t)(__attribute__((address_space(3))) bf16*)&Vlds[1][0];

  for (int ti = 0; ti < NKV; ++ti) {
    const int kv = ti * 64;
    __syncthreads();
    if (ti + 1 < NKV) stage(cur ^ 1, kv + 64);

    const char* Kl = (const char*)&Klds[cur][0];

    f32x4 sc[4];
#pragma unroll
    for (int kb = 0; kb < 4; ++kb) {
      const int row = kb * 16 + fr;
      const bf16x8 kf0 =
          *(const bf16x8*)(Kl + row * 128 + ((fq ^ (row & 7)) << 4));
      const bf16x8 kf1 =
          *(const bf16x8*)(Kl + row * 128 + (((4 + fq) ^ (row & 7)) << 4));
      f32x4 s = {0.f, 0.f, 0.f, 0.f};
      s = mfma16(qf0, kf0, s);
      s = mfma16(qf1, kf1, s);
      sc[kb] = s;
    }

    float fac[4];
#pragma unroll
    for (int r = 0; r < 4; ++r) {
      const int q = fq * 4 + r;
      float s[4];
#pragma unroll
      for (int kb = 0; kb < 4; ++kb) {
        const bool valid = (kv + kb * 16 + fr) < KEEP;
        s[kb] = valid ? sc[kb][r] * 0.125f : -INFINITY;
      }
      float mx = fmaxf(fmaxf(s[0], s[1]), fmaxf(s[2], s[3]));
      mx = fmaxf(mx, __shfl_xor(mx, 1));
      mx = fmaxf(mx, __shfl_xor(mx, 2));
      mx = fmaxf(mx, __shfl_xor(mx, 4));
      mx = fmaxf(mx, __shfl_xor(mx, 8));
      const float mnew = fmaxf(mrow[r], mx);
      float ps = 0.f;
#pragma unroll
      for (int kb = 0; kb < 4; ++kb) {
        const float pv = __expf(s[kb] - mnew);
        ps += pv;
        const int chunk = kb * 2 + (fr >> 3);
        *(bf16*)(pw + q * 128 + ((chunk ^ (q & 7)) << 4) + (fr & 7) * 2) =
            (bf16)pv;
      }
      ps += __shfl_xor(ps, 1);
      ps += __shfl_xor(ps, 2);
      ps += __shfl_xor(ps, 4);
      ps += __shfl_xor(ps, 8);
      const float f = __expf(mrow[r] - mnew);
      lrow[r] = lrow[r] * f + ps;
      mrow[r] = mnew;
      fac[r] = f;
    }
#pragma unroll
    for (int db = 0; db < 4; ++db) {
      o[db][0] *= fac[0]; o[db][1] *= fac[1];
      o[db][2] *= fac[2]; o[db][3] *= fac[3];
    }

    const unsigned vb =
        (cur ? vbase_lds1 : vbase_lds0) + ((unsigned)(lane >> 4) << 7);
#pragma unroll
    for (int kb32 = 0; kb32 < 2; ++kb32) {
      const bf16x8 pa = *(const bf16x8*)(
          pw + fr * 128 + (((kb32 * 4 + fq) ^ (fr & 7)) << 4));
      const unsigned addr = vb + kb32 * 1024;
      bf16x4 t0, t1, t2, t3, t4, t5, t6, t7;
      asm volatile(
          "ds_read_b64_tr_b16 %0, %8 offset:0\n\t"
          "ds_read_b64_tr_b16 %1, %8 offset:128\n\t"
          "ds_read_b64_tr_b16 %2, %8 offset:2048\n\t"
          "ds_read_b64_tr_b16 %3, %8 offset:2176\n\t"
          "ds_read_b64_tr_b16 %4, %8 offset:4096\n\t"
          "ds_read_b64_tr_b16 %5, %8 offset:4224\n\t"
          "ds_read_b64_tr_b16 %6, %8 offset:6144\n\t"
          "ds_read_b64_tr_b16 %7, %8 offset:6272\n\t"
          "s_waitcnt lgkmcnt(0)"
          : "=&v"(t0), "=&v"(t1), "=&v"(t2), "=&v"(t3),
            "=&v"(t4), "=&v"(t5), "=&v"(t6), "=&v"(t7)
          : "v"(addr));
      const bf16x8 vf0 = __builtin_shufflevector(t0, t1, 0, 1, 2, 3, 4, 5, 6, 7);
      const bf16x8 vf1 = __builtin_shufflevector(t2, t3, 0, 1, 2, 3, 4, 5, 6, 7);
      const bf16x8 vf2 = __builtin_shufflevector(t4, t5, 0, 1, 2, 3, 4, 5, 6, 7);
      const bf16x8 vf3 = __builtin_shufflevector(t6, t7, 0, 1, 2, 3, 4, 5, 6, 7);
      o[0] = mfma16(pa, vf0, o[0]);
      o[1] = mfma16(pa, vf1, o[1]);
      o[2] = mfma16(pa, vf2, o[2]);
      o[3] = mfma16(pa, vf3, o[3]);
    }
    cur ^= 1;
  }

#pragma unroll
  for (int r = 0; r < 4; ++r) {
    const int q = wq0 + fq * 4 + r;
    if (q < KEEP) {
      const float inv = 1.f / lrow[r];
#pragma unroll
      for (int db = 0; db < 4; ++db)
        out[(rowbase + q) * (size_t)D_ + h * 64 + db * 16 + fr] =
            (bf16)(o[db][r] * inv);
    }
  }
}

// ----------------------------------------------------------------------------
extern "C" void kernel_launch(void* const* d_in, const int* in_sizes, int n_in,
                              void* d_out, int out_size, void* d_ws, size_t ws_size,
                              hipStream_t stream)
{
  (void)in_sizes; (void)n_in; (void)out_size; (void)ws_size;
  const float* x      = (const float*)d_in[0];
  const float* t_emb  = (const float*)d_in[1];
  const float* tr_w1  = (const float*)d_in[2];
  const float* tr_b1  = (const float*)d_in[3];
  const float* tr_w2  = (const float*)d_in[4];
  const float* tr_b2  = (const float*)d_in[5];
  const float* ln1_w  = (const float*)d_in[6];
  const float* ln1_b  = (const float*)d_in[7];
  const float* ln2_w  = (const float*)d_in[8];
  const float* ln2_b  = (const float*)d_in[9];
  const float* in_w   = (const float*)d_in[10];
  const float* in_b   = (const float*)d_in[11];
  const float* out_w  = (const float*)d_in[12];
  const float* out_b  = (const float*)d_in[13];
  const float* f1_w   = (const float*)d_in[14];
  const float* f1_b   = (const float*)d_in[15];
  const float* f2_w   = (const float*)d_in[16];
  const float* f2_b   = (const float*)d_in[17];
  const float* gate_a = (const float*)d_in[18];
  const float* gate_f = (const float*)d_in[19];

  char* ws = (char*)d_ws;
  size_t off = 0;
  auto alloc = [&](size_t bytes) -> char* {
    char* p = ws + off;
    off = (off + bytes + 255) & ~(size_t)255;
    return p;
  };
  double* imp  = (double*)alloc((size_t)B_ * S_ * 8);
  int* rank    = (int*)alloc((size_t)B_ * S_ * 4);
  int* idx     = (int*)alloc((size_t)B_ * KEEP * 4);
  float* p1    = (float*)alloc((size_t)B_ * 2 * D_ * 4);
  float* p2    = (float*)alloc((size_t)B_ * 2 * D_ * 4);
  bf16* w_in   = (bf16*)alloc((size_t)3 * D_ * D_ * 2);
  bf16* w_out  = (bf16*)alloc((size_t)D_ * D_ * 2);
  bf16* w_f1   = (bf16*)alloc((size_t)DFF_ * D_ * 2);
  bf16* w_f2   = (bf16*)alloc((size_t)D_ * DFF_ * 2);
  bf16* h_bf   = (bf16*)alloc((size_t)MPAD * D_ * 2);
  bf16* big    = (bf16*)alloc((size_t)MPAD * (3 * D_ + D_) * 2);
  bf16* qkv    = big;
  bf16* attn   = big + (size_t)MPAD * 3 * D_;
  bf16* ffn1   = big;   // overlays qkv+attn (both dead by then)

  hipMemcpyAsync(d_out, x, (size_t)B_ * S_ * D_ * 4, hipMemcpyDeviceToDevice, stream);

  k_importance<<<B_ * S_, 256, 0, stream>>>(x, tr_w1, tr_b1, tr_w2, tr_b2, imp);
  k_rank<<<B_ * 32, 256, 0, stream>>>(imp, rank);
  k_compact<<<B_, 256, 0, stream>>>(rank, idx);

  k_condproj<<<(B_ * 2 * D_) / 4, 256, 0, stream>>>(t_emb, ln1_w, ln1_b, p1);
  k_condproj<<<(B_ * 2 * D_) / 4, 256, 0, stream>>>(t_emb, ln2_w, ln2_b, p2);

  k_f2b<<<(3 * D_ * D_ / 4 + 255) / 256, 256, 0, stream>>>(in_w, w_in, 3 * D_ * D_ / 4);
  k_f2b<<<(D_ * D_ / 4 + 255) / 256, 256, 0, stream>>>(out_w, w_out, D_ * D_ / 4);
  k_f2b<<<(DFF_ * D_ / 4 + 255) / 256, 256, 0, stream>>>(f1_w, w_f1, DFF_ * D_ / 4);
  k_f2b<<<(DFF_ * D_ / 4 + 255) / 256, 256, 0, stream>>>(f2_w, w_f2, DFF_ * D_ / 4);

  k_adaln<<<MPAD, 256, 0, stream>>>(x, idx, p1, h_bf);
  k_gemm<128, 0><<<45 * 24, 256, 0, stream>>>(
      h_bf, w_in, in_b, qkv, nullptr, nullptr, nullptr, 3 * D_, D_, 24);
  k_attn<<<dim3(QT64, H_, B_), 256, 0, stream>>>(qkv, attn);
  k_gemm<64, 2><<<45 * 16, 256, 0, stream>>>(
      attn, w_out, out_b, nullptr, gate_a, idx, (float*)d_out, D_, D_, 16);
  k_adaln<<<MPAD, 256, 0, stream>>>((const float*)d_out, idx, p2, h_bf);
  k_gemm<128, 1><<<45 * 32, 256, 0, stream>>>(
      h_bf, w_f1, f1_b, ffn1, nullptr, nullptr, nullptr, DFF_, D_, 32);
  k_gemm<64, 2><<<45 * 16, 256, 0, stream>>>(
      ffn1, w_f2, f2_b, nullptr, gate_f, idx, (float*)d_out, D_, DFF_, 16);
}

// Round 4
// 521.791 us; speedup vs baseline: 1.5798x; 1.0672x over previous
//
#include <hip/hip_runtime.h>
#include <hip/hip_bf16.h>
#include <cmath>
#include <cstdint>

typedef __bf16 bf16;
typedef __bf16 bf16x8 __attribute__((ext_vector_type(8)));
typedef __bf16 bf16x4 __attribute__((ext_vector_type(4)));
typedef float  f32x4  __attribute__((ext_vector_type(4)));

constexpr int B_   = 4;
constexpr int S_   = 2048;
constexpr int D_   = 1024;
constexpr int H_   = 16;
constexpr int DFF_ = 4096;
constexpr int TD_  = 256;
constexpr int KEEP = 1433;             // int(2048*0.7)
constexpr int M_TOT = B_ * KEEP;       // 5732
constexpr int MPAD  = 5760;            // 45*128
constexpr int QT64  = (KEEP + 63) / 64; // 23
constexpr int NKV   = (KEEP + 63) / 64; // 23
constexpr float EPS = 1e-5f;
// 1/sqrt(64) * log2(e): folded into Q in the QKV epilogue; attn uses exp2.
constexpr float QSCALE = 0.18033688011112042f;

__device__ __forceinline__ f32x4 mfma16(bf16x8 a, bf16x8 b, f32x4 c) {
  return __builtin_amdgcn_mfma_f32_16x16x32_bf16(a, b, c, 0, 0, 0);
}

#define GLOAD_LDS(gp, lp)                                                     \
  __builtin_amdgcn_global_load_lds(                                           \
      (const __attribute__((address_space(1))) void*)(gp),                    \
      (__attribute__((address_space(3))) void*)(lp), 16, 0, 0)

// ---------------- token importance (fp64 accumulation for exact ranking) ----
__global__ __launch_bounds__(256) void k_importance(
    const float* __restrict__ x, const float* __restrict__ w1,
    const float* __restrict__ b1, const float* __restrict__ w2,
    const float* __restrict__ b2, double* __restrict__ imp)
{
  const int tok = blockIdx.x;            // b*S + s
  const float* xr = x + (size_t)tok * D_;
  __shared__ float xs[D_];
  __shared__ double part[8][32];
  __shared__ double sacc[32];
  const int t = threadIdx.x;
  for (int i = t; i < D_ / 4; i += 256)
    ((float4*)xs)[i] = ((const float4*)xr)[i];
  __syncthreads();
  const int o = t & 31;       // which of 32 hidden units
  const int ck = t >> 5;      // 0..7 chunk of 128 cols
  const float* wr = w1 + (size_t)o * D_ + ck * 128;
  const float* xc = xs + ck * 128;
  double acc = 0.0;
  for (int c = 0; c < 128; ++c) acc += (double)xc[c] * (double)wr[c];
  part[ck][o] = acc;
  __syncthreads();
  if (t < 32) {
    double s = 0.0;
    for (int c = 0; c < 8; ++c) s += part[c][t];
    s += (double)b1[t];
    double sv = s / (1.0 + exp(-s));    // silu
    sacc[t] = sv * (double)w2[t];
  }
  __syncthreads();
  if (t == 0) {
    double r = 0.0;
    for (int i = 0; i < 32; ++i) r += sacc[i];
    imp[tok] = r + (double)b2[0];
  }
}

// ---------------- rank: #(greater) or (equal && earlier) ---------------------
__global__ __launch_bounds__(256) void k_rank(const double* __restrict__ imp,
                                              int* __restrict__ rank)
{
  const int b = blockIdx.x >> 5;
  const int seg = blockIdx.x & 31;     // 64 tokens per block
  __shared__ double vals[S_];
  const double* ib = imp + (size_t)b * S_;
  for (int i = threadIdx.x; i < S_ / 2; i += 256)
    ((double2*)vals)[i] = ((const double2*)ib)[i];
  __syncthreads();
  const int tl = threadIdx.x >> 2;     // token within segment
  const int part = threadIdx.x & 3;    // quarter of the scan
  const int s = seg * 64 + tl;
  const double v = vals[s];
  int cnt = 0;
  for (int j = part * 512; j < (part + 1) * 512; ++j) {
    double u = vals[j];
    cnt += (u > v) || (u == v && j < s);
  }
  cnt += __shfl_xor(cnt, 1);
  cnt += __shfl_xor(cnt, 2);
  if (part == 0) rank[b * S_ + s] = cnt;
}

// ---------------- compact kept indices (ascending) ---------------------------
__global__ __launch_bounds__(256) void k_compact(const int* __restrict__ rank,
                                                 int* __restrict__ idx)
{
  const int b = blockIdx.x;
  __shared__ int wcnt[4];
  __shared__ int base_s;
  if (threadIdx.x == 0) base_s = 0;
  __syncthreads();
  const int t = threadIdx.x, lane = t & 63, w = t >> 6;
  for (int c = 0; c < S_ / 256; ++c) {
    const int s = c * 256 + t;
    const bool kept = rank[b * S_ + s] < KEEP;
    unsigned long long m = __ballot(kept);
    int piw = __popcll(m & ((1ull << lane) - 1ull));
    if (lane == 0) wcnt[w] = __popcll(m);
    __syncthreads();
    int off = base_s;
    for (int i = 0; i < w; ++i) off += wcnt[i];
    if (kept) idx[b * KEEP + off + piw] = s;
    __syncthreads();
    if (t == 0) base_s += wcnt[0] + wcnt[1] + wcnt[2] + wcnt[3];
    __syncthreads();
  }
}

// ---------------- cond projection: p = silu(t_emb) @ W.T + b ----------------
__global__ __launch_bounds__(256) void k_condproj(
    const float* __restrict__ temb, const float* __restrict__ W,
    const float* __restrict__ bias, float* __restrict__ p)
{
  const int gw = (int)((blockIdx.x * 256 + threadIdx.x) >> 6);
  const int lane = threadIdx.x & 63;
  const int b = gw >> 11;          // 2048 outputs per batch
  const int row = gw & 2047;
  const float* te = temb + (size_t)b * TD_;
  const float* wr = W + (size_t)row * TD_;
  float acc = 0.f;
  for (int i = lane; i < TD_; i += 64) {
    float c = te[i];
    acc += (c / (1.f + __expf(-c))) * wr[i];
  }
  for (int o = 32; o > 0; o >>= 1) acc += __shfl_down(acc, o);
  if (lane == 0) p[(size_t)b * 2 * D_ + row] = acc + bias[row];
}

// ---------------- fp32 -> bf16 weight cast ----------------------------------
__global__ void k_f2b(const float* __restrict__ src, bf16* __restrict__ dst, int n4)
{
  int i = blockIdx.x * 256 + threadIdx.x;
  if (i < n4) {
    float4 v = ((const float4*)src)[i];
    bf16x4 o = {(bf16)v.x, (bf16)v.y, (bf16)v.z, (bf16)v.w};
    ((bf16x4*)dst)[i] = o;
  }
}

// ---------------- gather + adaLN -> bf16 -------------------------------------
__global__ __launch_bounds__(256) void k_adaln(
    const float* __restrict__ xsrc, const int* __restrict__ idx,
    const float* __restrict__ p, bf16* __restrict__ hout)
{
  const int r = blockIdx.x, t = threadIdx.x;
  bf16* orow = hout + (size_t)r * D_;
  if (r >= M_TOT) {
    bf16x4 z = {(bf16)0.f, (bf16)0.f, (bf16)0.f, (bf16)0.f};
    ((bf16x4*)orow)[t] = z;
    return;
  }
  const int b = r / KEEP, j = r - b * KEEP;
  const int s = idx[b * KEEP + j];
  const float* xr = xsrc + ((size_t)(b * S_ + s)) * D_;
  float4 v = ((const float4*)xr)[t];
  __shared__ float red[8];
  float sum = v.x + v.y + v.z + v.w;
  for (int o = 32; o > 0; o >>= 1) sum += __shfl_down(sum, o);
  const int lane = t & 63, w = t >> 6;
  if (lane == 0) red[w] = sum;
  __syncthreads();
  const float mu = (red[0] + red[1] + red[2] + red[3]) * (1.f / D_);
  const float dx = v.x - mu, dy = v.y - mu, dz = v.z - mu, dw = v.w - mu;
  float vs = dx * dx + dy * dy + dz * dz + dw * dw;
  for (int o = 32; o > 0; o >>= 1) vs += __shfl_down(vs, o);
  if (lane == 0) red[4 + w] = vs;
  __syncthreads();
  const float rstd = rsqrtf((red[4] + red[5] + red[6] + red[7]) * (1.f / D_) + EPS);
  const float* gp = p + (size_t)b * 2 * D_;
  float4 g  = ((const float4*)gp)[t];
  float4 be = ((const float4*)(gp + D_))[t];
  bf16x4 o;
  o[0] = (bf16)(dx * rstd * (1.f + g.x) + be.x);
  o[1] = (bf16)(dy * rstd * (1.f + g.y) + be.y);
  o[2] = (bf16)(dz * rstd * (1.f + g.z) + be.z);
  o[3] = (bf16)(dw * rstd * (1.f + g.w) + be.w);
  ((bf16x4*)orow)[t] = o;
}

// ---------------- GEMM: C[m][n] = sum_k A[m][k] * W[n][k]  (+ epilogues) -----
// MODE 0: bias (+QSCALE on the Q third) -> bf16. MODE 1: bias+gelu -> bf16.
// MODE 2: bias, then resid[row(m)][n] += gate[n]*v (gathered residual).
template <int BN, int MODE>
__global__ __launch_bounds__(256) void k_gemm(
    const bf16* __restrict__ A, const bf16* __restrict__ W,
    const float* __restrict__ bias, bf16* __restrict__ Cbf,
    const float* __restrict__ gate, const int* __restrict__ idx,
    float* __restrict__ resid, int N, int K, int gn)
{
  constexpr int WN = BN / 2;      // per-wave N span
  constexpr int NJ = WN / 16;     // N fragments per wave
  __shared__ bf16 As[2][128 * 64];
  __shared__ bf16 Ws[2][BN * 64];
  const int t = threadIdx.x, lane = t & 63;
  const int w = t >> 6, wr = w >> 1, wc = w & 1;
  const int fr = lane & 15, fq = lane >> 4;

  // bijective XCD-contiguous remap (m204)
  const int nwg = gridDim.x, orig = blockIdx.x;
  const int q8 = nwg >> 3, r8 = nwg & 7;
  const int xc = orig & 7, pos = orig >> 3;
  const int wgid = (xc < r8 ? xc * (q8 + 1) : r8 * (q8 + 1) + (xc - r8) * q8) + pos;
  const int bm = wgid / gn, bn = wgid - bm * gn;

  const bf16* Ab = A + (size_t)bm * 128 * K;
  const bf16* Wb = W + (size_t)bn * BN * K;

  auto stage = [&](int buf, int kt) {
    const int ko = kt * 64;
#pragma unroll
    for (int it = 0; it < 4; ++it) {
      const int e = it * 256 + t;
      const int row = e >> 3, pc = e & 7;
      const int lc = pc ^ (row & 7);
      GLOAD_LDS(Ab + (size_t)row * K + ko + lc * 8, &As[buf][0] + e * 8);
    }
#pragma unroll
    for (int it = 0; it < BN / 32; ++it) {
      const int e = it * 256 + t;
      const int row = e >> 3, pc = e & 7;
      const int lc = pc ^ (row & 7);
      GLOAD_LDS(Wb + (size_t)row * K + ko + lc * 8, &Ws[buf][0] + e * 8);
    }
  };

  f32x4 acc[4][NJ] = {};
  stage(0, 0);
  const int nkt = K >> 6;
  int cur = 0;
  for (int kt = 0; kt < nkt; ++kt) {
    __syncthreads();                   // stage(cur) landed; prev reads done
    if (kt + 1 < nkt) stage(cur ^ 1, kt + 1);
    const char* Al = (const char*)&As[cur][0];
    const char* Wl = (const char*)&Ws[cur][0];
#pragma unroll
    for (int kk = 0; kk < 2; ++kk) {
      bf16x8 af[4], wf[NJ];
#pragma unroll
      for (int i = 0; i < 4; ++i)
        af[i] = *(const bf16x8*)(Al + (wr * 64 + i * 16 + fr) * 128 +
                                 (((kk * 4 + fq) ^ (fr & 7)) << 4));
#pragma unroll
      for (int j = 0; j < NJ; ++j)
        wf[j] = *(const bf16x8*)(Wl + (wc * WN + j * 16 + fr) * 128 +
                                 (((kk * 4 + fq) ^ (fr & 7)) << 4));
#pragma unroll
      for (int i = 0; i < 4; ++i)
#pragma unroll
        for (int j = 0; j < NJ; ++j)
          acc[i][j] = mfma16(af[i], wf[j], acc[i][j]);
    }
    cur ^= 1;
  }

#pragma unroll
  for (int i = 0; i < 4; ++i) {
#pragma unroll
    for (int j = 0; j < NJ; ++j) {
#pragma unroll
      for (int r = 0; r < 4; ++r) {
        const int m = bm * 128 + wr * 64 + i * 16 + fq * 4 + r;
        const int n = bn * BN + wc * WN + j * 16 + fr;
        float v = acc[i][j][r] + bias[n];
        if (MODE == 0) {
          if (n < D_) v *= QSCALE;     // pre-scale Q for exp2-domain softmax
          Cbf[(size_t)m * N + n] = (bf16)v;
        } else if (MODE == 1) {
          float gl = 0.5f * v * (1.f + erff(v * 0.70710678118654752f));
          Cbf[(size_t)m * N + n] = (bf16)gl;
        } else {
          if (m < M_TOT) {
            const int b = m / KEEP, jj = m - b * KEEP;
            const int s = idx[b * KEEP + jj];
            resid[((size_t)(b * S_ + s)) * D_ + n] += gate[n] * v;
          }
        }
      }
    }
  }
}

// ---------------- flash attention: swapped-QK^T, in-register softmax ---------
// S^T = mfma(K_perm, Q): lane fr owns q-column fr; the K-row permutation
// sigma_f makes S^T registers land exactly in PV B-fragment k-order, so
// softmax + P never touch LDS or cross-lane (beyond 2 shfl_xor reduces).
__global__ __launch_bounds__(256) void k_attn(const bf16* __restrict__ qkv,
                                              bf16* __restrict__ out)
{
  __shared__ bf16 Klds[2][64 * 64];
  __shared__ bf16 Vlds[2][64 * 64];

  const int t = threadIdx.x;
  const int lane = t & 63, w = t >> 6;
  const int fr = lane & 15, fq = lane >> 4;
  const int qt = blockIdx.x, h = blockIdx.y, b = blockIdx.z;
  const size_t rowbase = (size_t)b * KEEP;
  const size_t RS = 3 * D_;
  const bf16* kbase = qkv + rowbase * RS + D_ + h * 64;
  const bf16* vbase = qkv + rowbase * RS + 2 * D_ + h * 64;

  const int wq0 = qt * 64 + w * 16;
  const int qrow = min(wq0 + fr, KEEP - 1);
  const bf16* qp = qkv + (rowbase + qrow) * RS + h * 64 + fq * 8;
  const bf16x8 qf0 = *(const bf16x8*)qp;          // Q as B-operand, d<32
  const bf16x8 qf1 = *(const bf16x8*)(qp + 32);   // d>=32

  f32x4 o[4] = {};
  float mrow = -INFINITY, lrow = 0.f;

  auto stage = [&](int buf, int kv) {
#pragma unroll
    for (int rnd = 0; rnd < 2; ++rnd) {
      const int p = rnd * 256 + t;
      {
        // K: row-major [64][64]; 16B-chunk XOR-swizzled by (row&7)^(row>>3)
        const int row = p >> 3, c8p = p & 7;
        const int c8 = c8p ^ ((row & 7) ^ (row >> 3));
        const int gr = min(kv + row, KEEP - 1);
        GLOAD_LDS(kbase + (size_t)gr * RS + c8 * 8, &Klds[buf][0] + p * 8);
      }
      {
        // V: subtiled [db][ksub][4][16] for tr-read
        const int db = p >> 7, ksub = (p >> 3) & 15, jr = (p >> 1) & 3,
                  c8lo = p & 1;
        const int vrow = ksub * 4 + jr, vc8 = db * 2 + c8lo;
        const int gr = min(kv + vrow, KEEP - 1);
        GLOAD_LDS(vbase + (size_t)gr * RS + vc8 * 8, &Vlds[buf][0] + p * 8);
      }
    }
  };

  stage(0, 0);
  int cur = 0;

  const unsigned vbase_lds0 =
      (unsigned)(size_t)(__attribute__((address_space(3))) bf16*)&Vlds[0][0];
  const unsigned vbase_lds1 =
      (unsigned)(size_t)(__attribute__((address_space(3))) bf16*)&Vlds[1][0];

  for (int ti = 0; ti < NKV; ++ti) {
    const int kv = ti * 64;
    __syncthreads();                   // stage(cur) landed; prev reads done
    if (ti + 1 < NKV) stage(cur ^ 1, kv + 64);

    const char* Kl = (const char*)&Klds[cur][0];

    // ---- S^T[k][q] fragments; fragment f covers k = sigma_f(i)
    f32x4 sc[4];
#pragma unroll
    for (int f = 0; f < 4; ++f) {
      const int row = ((f >> 1) << 5) + ((fr >> 2) << 3) + ((f & 1) << 1) +
                      (fr & 1) + (((fr >> 1) & 1) << 2);
      const int swz = (row & 7) ^ (row >> 3);
      const bf16x8 kf0 = *(const bf16x8*)(Kl + row * 128 + ((fq ^ swz) << 4));
      const bf16x8 kf1 =
          *(const bf16x8*)(Kl + row * 128 + (((fq ^ 4) ^ swz) << 4));
      f32x4 s = {0.f, 0.f, 0.f, 0.f};
      s = mfma16(kf0, qf0, s);   // A = K rows (k), B = Q cols (q)
      s = mfma16(kf1, qf1, s);
      sc[f] = s;
    }

    // ---- in-register online softmax for q = fr (lane-local row)
    if (ti == NKV - 1) {
#pragma unroll
      for (int f = 0; f < 4; ++f)
#pragma unroll
        for (int r = 0; r < 4; ++r) {
          const int kl = ((f >> 1) << 5) + (fq << 3) + ((f & 1) << 1) +
                         (r & 1) + ((r >> 1) << 2);
          if (kv + kl >= KEEP) sc[f][r] = -INFINITY;
        }
    }
    float mx = sc[0][0];
#pragma unroll
    for (int f = 0; f < 4; ++f)
#pragma unroll
      for (int r = 0; r < 4; ++r) mx = fmaxf(mx, sc[f][r]);
    mx = fmaxf(mx, __shfl_xor(mx, 16));
    mx = fmaxf(mx, __shfl_xor(mx, 32));
    const float mnew = fmaxf(mrow, mx);
    float ps = 0.f;
    bf16 pe[4][4];
#pragma unroll
    for (int f = 0; f < 4; ++f)
#pragma unroll
      for (int r = 0; r < 4; ++r) {
        const float pv = exp2f(sc[f][r] - mnew);
        ps += pv;
        pe[f][r] = (bf16)pv;
      }
    ps += __shfl_xor(ps, 16);
    ps += __shfl_xor(ps, 32);
    const float fac = exp2f(mrow - mnew);
    lrow = lrow * fac + ps;
    mrow = mnew;
#pragma unroll
    for (int db = 0; db < 4; ++db) {
      o[db][0] *= fac; o[db][1] *= fac; o[db][2] *= fac; o[db][3] *= fac;
    }

    // ---- PV: O^T = mfma(A = V^T via tr-read, B = P^T from registers)
    const bf16x8 pb[2] = {
        {pe[0][0], pe[0][1], pe[1][0], pe[1][1],
         pe[0][2], pe[0][3], pe[1][2], pe[1][3]},
        {pe[2][0], pe[2][1], pe[3][0], pe[3][1],
         pe[2][2], pe[2][3], pe[3][2], pe[3][3]}};
    const unsigned vb =
        (cur ? vbase_lds1 : vbase_lds0) + ((unsigned)fq << 7);
#pragma unroll
    for (int c = 0; c < 2; ++c) {
      const unsigned addr = vb + c * 1024;
      bf16x4 t0, t1, t2, t3, t4, t5, t6, t7;
      asm volatile(
          "ds_read_b64_tr_b16 %0, %8 offset:0\n\t"
          "ds_read_b64_tr_b16 %1, %8 offset:128\n\t"
          "ds_read_b64_tr_b16 %2, %8 offset:2048\n\t"
          "ds_read_b64_tr_b16 %3, %8 offset:2176\n\t"
          "ds_read_b64_tr_b16 %4, %8 offset:4096\n\t"
          "ds_read_b64_tr_b16 %5, %8 offset:4224\n\t"
          "ds_read_b64_tr_b16 %6, %8 offset:6144\n\t"
          "ds_read_b64_tr_b16 %7, %8 offset:6272\n\t"
          "s_waitcnt lgkmcnt(0)"
          : "=&v"(t0), "=&v"(t1), "=&v"(t2), "=&v"(t3),
            "=&v"(t4), "=&v"(t5), "=&v"(t6), "=&v"(t7)
          : "v"(addr));
      const bf16x8 vf0 = __builtin_shufflevector(t0, t1, 0, 1, 2, 3, 4, 5, 6, 7);
      const bf16x8 vf1 = __builtin_shufflevector(t2, t3, 0, 1, 2, 3, 4, 5, 6, 7);
      const bf16x8 vf2 = __builtin_shufflevector(t4, t5, 0, 1, 2, 3, 4, 5, 6, 7);
      const bf16x8 vf3 = __builtin_shufflevector(t6, t7, 0, 1, 2, 3, 4, 5, 6, 7);
      o[0] = mfma16(vf0, pb[c], o[0]);
      o[1] = mfma16(vf1, pb[c], o[1]);
      o[2] = mfma16(vf2, pb[c], o[2]);
      o[3] = mfma16(vf3, pb[c], o[3]);
    }
    cur ^= 1;
  }

  // ---- epilogue: lane fr owns q; O^T reg (db, r) -> d = db*16 + fq*4 + r
  const int q = wq0 + fr;
  if (q < KEEP) {
    const float inv = 1.f / lrow;
#pragma unroll
    for (int db = 0; db < 4; ++db) {
      bf16x4 wv = {(bf16)(o[db][0] * inv), (bf16)(o[db][1] * inv),
                   (bf16)(o[db][2] * inv), (bf16)(o[db][3] * inv)};
      *(bf16x4*)(out + (rowbase + q) * (size_t)D_ + h * 64 + db * 16 + fq * 4) =
          wv;
    }
  }
}

// ----------------------------------------------------------------------------
extern "C" void kernel_launch(void* const* d_in, const int* in_sizes, int n_in,
                              void* d_out, int out_size, void* d_ws, size_t ws_size,
                              hipStream_t stream)
{
  (void)in_sizes; (void)n_in; (void)out_size; (void)ws_size;
  const float* x      = (const float*)d_in[0];
  const float* t_emb  = (const float*)d_in[1];
  const float* tr_w1  = (const float*)d_in[2];
  const float* tr_b1  = (const float*)d_in[3];
  const float* tr_w2  = (const float*)d_in[4];
  const float* tr_b2  = (const float*)d_in[5];
  const float* ln1_w  = (const float*)d_in[6];
  const float* ln1_b  = (const float*)d_in[7];
  const float* ln2_w  = (const float*)d_in[8];
  const float* ln2_b  = (const float*)d_in[9];
  const float* in_w   = (const float*)d_in[10];
  const float* in_b   = (const float*)d_in[11];
  const float* out_w  = (const float*)d_in[12];
  const float* out_b  = (const float*)d_in[13];
  const float* f1_w   = (const float*)d_in[14];
  const float* f1_b   = (const float*)d_in[15];
  const float* f2_w   = (const float*)d_in[16];
  const float* f2_b   = (const float*)d_in[17];
  const float* gate_a = (const float*)d_in[18];
  const float* gate_f = (const float*)d_in[19];

  char* ws = (char*)d_ws;
  size_t off = 0;
  auto alloc = [&](size_t bytes) -> char* {
    char* p = ws + off;
    off = (off + bytes + 255) & ~(size_t)255;
    return p;
  };
  double* imp  = (double*)alloc((size_t)B_ * S_ * 8);
  int* rank    = (int*)alloc((size_t)B_ * S_ * 4);
  int* idx     = (int*)alloc((size_t)B_ * KEEP * 4);
  float* p1    = (float*)alloc((size_t)B_ * 2 * D_ * 4);
  float* p2    = (float*)alloc((size_t)B_ * 2 * D_ * 4);
  bf16* w_in   = (bf16*)alloc((size_t)3 * D_ * D_ * 2);
  bf16* w_out  = (bf16*)alloc((size_t)D_ * D_ * 2);
  bf16* w_f1   = (bf16*)alloc((size_t)DFF_ * D_ * 2);
  bf16* w_f2   = (bf16*)alloc((size_t)D_ * DFF_ * 2);
  bf16* h_bf   = (bf16*)alloc((size_t)MPAD * D_ * 2);
  bf16* big    = (bf16*)alloc((size_t)MPAD * (3 * D_ + D_) * 2);
  bf16* qkv    = big;
  bf16* attn   = big + (size_t)MPAD * 3 * D_;
  bf16* ffn1   = big;   // overlays qkv+attn (both dead by then)

  hipMemcpyAsync(d_out, x, (size_t)B_ * S_ * D_ * 4, hipMemcpyDeviceToDevice, stream);

  k_importance<<<B_ * S_, 256, 0, stream>>>(x, tr_w1, tr_b1, tr_w2, tr_b2, imp);
  k_rank<<<B_ * 32, 256, 0, stream>>>(imp, rank);
  k_compact<<<B_, 256, 0, stream>>>(rank, idx);

  k_condproj<<<(B_ * 2 * D_) / 4, 256, 0, stream>>>(t_emb, ln1_w, ln1_b, p1);
  k_condproj<<<(B_ * 2 * D_) / 4, 256, 0, stream>>>(t_emb, ln2_w, ln2_b, p2);

  k_f2b<<<(3 * D_ * D_ / 4 + 255) / 256, 256, 0, stream>>>(in_w, w_in, 3 * D_ * D_ / 4);
  k_f2b<<<(D_ * D_ / 4 + 255) / 256, 256, 0, stream>>>(out_w, w_out, D_ * D_ / 4);
  k_f2b<<<(DFF_ * D_ / 4 + 255) / 256, 256, 0, stream>>>(f1_w, w_f1, DFF_ * D_ / 4);
  k_f2b<<<(DFF_ * D_ / 4 + 255) / 256, 256, 0, stream>>>(f2_w, w_f2, DFF_ * D_ / 4);

  k_adaln<<<MPAD, 256, 0, stream>>>(x, idx, p1, h_bf);
  k_gemm<128, 0><<<45 * 24, 256, 0, stream>>>(
      h_bf, w_in, in_b, qkv, nullptr, nullptr, nullptr, 3 * D_, D_, 24);
  k_attn<<<dim3(QT64, H_, B_), 256, 0, stream>>>(qkv, attn);
  k_gemm<64, 2><<<45 * 16, 256, 0, stream>>>(
      attn, w_out, out_b, nullptr, gate_a, idx, (float*)d_out, D_, D_, 16);
  k_adaln<<<MPAD, 256, 0, stream>>>((const float*)d_out, idx, p2, h_bf);
  k_gemm<128, 1><<<45 * 32, 256, 0, stream>>>(
      h_bf, w_f1, f1_b, ffn1, nullptr, nullptr, nullptr, DFF_, D_, 32);
  k_gemm<64, 2><<<45 * 16, 256, 0, stream>>>(
      ffn1, w_f2, f2_b, nullptr, gate_f, idx, (float*)d_out, D_, DFF_, 16);
}

// Round 5
// 457.847 us; speedup vs baseline: 1.8005x; 1.1397x over previous
//
#include <hip/hip_runtime.h>
#include <hip/hip_bf16.h>
#include <cmath>
#include <cstdint>

typedef __bf16 bf16;
typedef __bf16 bf16x8 __attribute__((ext_vector_type(8)));
typedef __bf16 bf16x4 __attribute__((ext_vector_type(4)));
typedef float  f32x4  __attribute__((ext_vector_type(4)));

constexpr int B_   = 4;
constexpr int S_   = 2048;
constexpr int D_   = 1024;
constexpr int H_   = 16;
constexpr int DFF_ = 4096;
constexpr int TD_  = 256;
constexpr int KEEP = 1433;             // int(2048*0.7)
constexpr int M_TOT = B_ * KEEP;       // 5732
constexpr int MPAD  = 5760;            // 45*128
constexpr int QT64  = (KEEP + 63) / 64; // 23
constexpr int NKV   = (KEEP + 63) / 64; // 23
constexpr float EPS = 1e-5f;
// 1/sqrt(64) * log2(e): folded into Q in the QKV epilogue; attn uses exp2.
constexpr float QSCALE = 0.18033688011112042f;

__device__ __forceinline__ f32x4 mfma16(bf16x8 a, bf16x8 b, f32x4 c) {
  return __builtin_amdgcn_mfma_f32_16x16x32_bf16(a, b, c, 0, 0, 0);
}

#define GLOAD_LDS(gp, lp)                                                     \
  __builtin_amdgcn_global_load_lds(                                           \
      (const __attribute__((address_space(1))) void*)(gp),                    \
      (__attribute__((address_space(3))) void*)(lp), 16, 0, 0)

// ---------------- importance GEMV: hidden[tok][u] = x[tok] . w1[u] (fp64) ---
// Wave = 4 tokens x 8 units, all-register, coalesced float4 loads.
__global__ __launch_bounds__(256) void k_impgemv(
    const float* __restrict__ x, const float* __restrict__ w1,
    double* __restrict__ hidden)
{
  const int lane = threadIdx.x & 63, w = threadIdx.x >> 6;
  const int tok0 = blockIdx.x * 16 + w * 4;
  const int u0 = blockIdx.y * 8;
  const float* xb = x + (size_t)tok0 * D_ + lane * 4;
  const float* wb = w1 + (size_t)u0 * D_ + lane * 4;
  double acc[4][8] = {};
#pragma unroll 2
  for (int c = 0; c < D_; c += 256) {
    float4 xv[4], wv[8];
#pragma unroll
    for (int i = 0; i < 4; ++i)
      xv[i] = *(const float4*)(xb + (size_t)i * D_ + c);
#pragma unroll
    for (int u = 0; u < 8; ++u)
      wv[u] = *(const float4*)(wb + (size_t)u * D_ + c);
#pragma unroll
    for (int i = 0; i < 4; ++i)
#pragma unroll
      for (int u = 0; u < 8; ++u) {
        acc[i][u] += (double)xv[i].x * (double)wv[u].x;
        acc[i][u] += (double)xv[i].y * (double)wv[u].y;
        acc[i][u] += (double)xv[i].z * (double)wv[u].z;
        acc[i][u] += (double)xv[i].w * (double)wv[u].w;
      }
  }
#pragma unroll
  for (int i = 0; i < 4; ++i)
#pragma unroll
    for (int u = 0; u < 8; ++u) {
      double s = acc[i][u];
      for (int o = 32; o > 0; o >>= 1) s += __shfl_xor(s, o);
      acc[i][u] = s;
    }
  if (lane == 0) {
#pragma unroll
    for (int i = 0; i < 4; ++i)
#pragma unroll
      for (int u = 0; u < 8; ++u)
        hidden[(size_t)(tok0 + i) * 32 + u0 + u] = acc[i][u];
  }
}

// ---------------- importance tail: imp = silu(hidden + b1) . w2 + b2 --------
__global__ __launch_bounds__(256) void k_imptail(
    const double* __restrict__ hidden, const float* __restrict__ b1,
    const float* __restrict__ w2, const float* __restrict__ b2,
    double* __restrict__ imp)
{
  const int tok = blockIdx.x * 256 + threadIdx.x;
  const double* hp = hidden + (size_t)tok * 32;
  double r = 0.0;
#pragma unroll
  for (int u = 0; u < 32; ++u) {
    double s = hp[u] + (double)b1[u];
    double sv = s / (1.0 + exp(-s));
    r += sv * (double)w2[u];
  }
  imp[tok] = r + (double)b2[0];
}

// ---------------- rank: #(greater) or (equal && earlier) ---------------------
__global__ __launch_bounds__(256) void k_rank(const double* __restrict__ imp,
                                              int* __restrict__ rank)
{
  const int b = blockIdx.x >> 5;
  const int seg = blockIdx.x & 31;     // 64 tokens per block
  __shared__ double vals[S_];
  const double* ib = imp + (size_t)b * S_;
  for (int i = threadIdx.x; i < S_ / 2; i += 256)
    ((double2*)vals)[i] = ((const double2*)ib)[i];
  __syncthreads();
  const int tl = threadIdx.x >> 2;     // token within segment
  const int part = threadIdx.x & 3;    // quarter of the scan
  const int s = seg * 64 + tl;
  const double v = vals[s];
  int cnt = 0;
  for (int j = part * 512; j < (part + 1) * 512; ++j) {
    double u = vals[j];
    cnt += (u > v) || (u == v && j < s);
  }
  cnt += __shfl_xor(cnt, 1);
  cnt += __shfl_xor(cnt, 2);
  if (part == 0) rank[b * S_ + s] = cnt;
}

// ---------------- compact kept indices (ascending) ---------------------------
__global__ __launch_bounds__(256) void k_compact(const int* __restrict__ rank,
                                                 int* __restrict__ idx)
{
  const int b = blockIdx.x;
  __shared__ int wcnt[4];
  __shared__ int base_s;
  if (threadIdx.x == 0) base_s = 0;
  __syncthreads();
  const int t = threadIdx.x, lane = t & 63, w = t >> 6;
  for (int c = 0; c < S_ / 256; ++c) {
    const int s = c * 256 + t;
    const bool kept = rank[b * S_ + s] < KEEP;
    unsigned long long m = __ballot(kept);
    int piw = __popcll(m & ((1ull << lane) - 1ull));
    if (lane == 0) wcnt[w] = __popcll(m);
    __syncthreads();
    int off = base_s;
    for (int i = 0; i < w; ++i) off += wcnt[i];
    if (kept) idx[b * KEEP + off + piw] = s;
    __syncthreads();
    if (t == 0) base_s += wcnt[0] + wcnt[1] + wcnt[2] + wcnt[3];
    __syncthreads();
  }
}

// ---------------- cond projection: p = silu(t_emb) @ W.T + b ----------------
__global__ __launch_bounds__(256) void k_condproj(
    const float* __restrict__ temb, const float* __restrict__ W,
    const float* __restrict__ bias, float* __restrict__ p)
{
  const int gw = (int)((blockIdx.x * 256 + threadIdx.x) >> 6);
  const int lane = threadIdx.x & 63;
  const int b = gw >> 11;          // 2048 outputs per batch
  const int row = gw & 2047;
  const float* te = temb + (size_t)b * TD_;
  const float* wr = W + (size_t)row * TD_;
  float acc = 0.f;
  for (int i = lane; i < TD_; i += 64) {
    float c = te[i];
    acc += (c / (1.f + __expf(-c))) * wr[i];
  }
  for (int o = 32; o > 0; o >>= 1) acc += __shfl_down(acc, o);
  if (lane == 0) p[(size_t)b * 2 * D_ + row] = acc + bias[row];
}

// ---------------- fp32 -> bf16 weight cast ----------------------------------
__global__ void k_f2b(const float* __restrict__ src, bf16* __restrict__ dst, int n4)
{
  int i = blockIdx.x * 256 + threadIdx.x;
  if (i < n4) {
    float4 v = ((const float4*)src)[i];
    bf16x4 o = {(bf16)v.x, (bf16)v.y, (bf16)v.z, (bf16)v.w};
    ((bf16x4*)dst)[i] = o;
  }
}

// ---------------- gather + adaLN -> bf16 -------------------------------------
__global__ __launch_bounds__(256) void k_adaln(
    const float* __restrict__ xsrc, const int* __restrict__ idx,
    const float* __restrict__ p, bf16* __restrict__ hout)
{
  const int r = blockIdx.x, t = threadIdx.x;
  bf16* orow = hout + (size_t)r * D_;
  if (r >= M_TOT) {
    bf16x4 z = {(bf16)0.f, (bf16)0.f, (bf16)0.f, (bf16)0.f};
    ((bf16x4*)orow)[t] = z;
    return;
  }
  const int b = r / KEEP, j = r - b * KEEP;
  const int s = idx[b * KEEP + j];
  const float* xr = xsrc + ((size_t)(b * S_ + s)) * D_;
  float4 v = ((const float4*)xr)[t];
  __shared__ float red[8];
  float sum = v.x + v.y + v.z + v.w;
  for (int o = 32; o > 0; o >>= 1) sum += __shfl_down(sum, o);
  const int lane = t & 63, w = t >> 6;
  if (lane == 0) red[w] = sum;
  __syncthreads();
  const float mu = (red[0] + red[1] + red[2] + red[3]) * (1.f / D_);
  const float dx = v.x - mu, dy = v.y - mu, dz = v.z - mu, dw = v.w - mu;
  float vs = dx * dx + dy * dy + dz * dz + dw * dw;
  for (int o = 32; o > 0; o >>= 1) vs += __shfl_down(vs, o);
  if (lane == 0) red[4 + w] = vs;
  __syncthreads();
  const float rstd = rsqrtf((red[4] + red[5] + red[6] + red[7]) * (1.f / D_) + EPS);
  const float* gp = p + (size_t)b * 2 * D_;
  float4 g  = ((const float4*)gp)[t];
  float4 be = ((const float4*)(gp + D_))[t];
  bf16x4 o;
  o[0] = (bf16)(dx * rstd * (1.f + g.x) + be.x);
  o[1] = (bf16)(dy * rstd * (1.f + g.y) + be.y);
  o[2] = (bf16)(dz * rstd * (1.f + g.z) + be.z);
  o[3] = (bf16)(dw * rstd * (1.f + g.w) + be.w);
  ((bf16x4*)orow)[t] = o;
}

// ---------------- GEMM: C[m][n] = sum_k A[m][k] * W[n][k]  (+ epilogues) -----
// MODE 0: bias (+QSCALE on the Q third) -> bf16. MODE 1: bias+gelu -> bf16.
// MODE 2: bias, then resid[row(m)][n] += gate[n]*v (gathered residual).
template <int BN, int MODE>
__global__ __launch_bounds__(256) void k_gemm(
    const bf16* __restrict__ A, const bf16* __restrict__ W,
    const float* __restrict__ bias, bf16* __restrict__ Cbf,
    const float* __restrict__ gate, const int* __restrict__ idx,
    float* __restrict__ resid, int N, int K, int gn)
{
  constexpr int WN = BN / 2;      // per-wave N span
  constexpr int NJ = WN / 16;     // N fragments per wave
  __shared__ bf16 As[2][128 * 64];
  __shared__ bf16 Ws[2][BN * 64];
  const int t = threadIdx.x, lane = t & 63;
  const int w = t >> 6, wr = w >> 1, wc = w & 1;
  const int fr = lane & 15, fq = lane >> 4;

  // bijective XCD-contiguous remap (m204)
  const int nwg = gridDim.x, orig = blockIdx.x;
  const int q8 = nwg >> 3, r8 = nwg & 7;
  const int xc = orig & 7, pos = orig >> 3;
  const int wgid = (xc < r8 ? xc * (q8 + 1) : r8 * (q8 + 1) + (xc - r8) * q8) + pos;
  const int bm = wgid / gn, bn = wgid - bm * gn;

  const bf16* Ab = A + (size_t)bm * 128 * K;
  const bf16* Wb = W + (size_t)bn * BN * K;

  auto stage = [&](int buf, int kt) {
    const int ko = kt * 64;
#pragma unroll
    for (int it = 0; it < 4; ++it) {
      const int e = it * 256 + t;
      const int row = e >> 3, pc = e & 7;
      const int lc = pc ^ (row & 7);
      GLOAD_LDS(Ab + (size_t)row * K + ko + lc * 8, &As[buf][0] + e * 8);
    }
#pragma unroll
    for (int it = 0; it < BN / 32; ++it) {
      const int e = it * 256 + t;
      const int row = e >> 3, pc = e & 7;
      const int lc = pc ^ (row & 7);
      GLOAD_LDS(Wb + (size_t)row * K + ko + lc * 8, &Ws[buf][0] + e * 8);
    }
  };

  f32x4 acc[4][NJ] = {};
  stage(0, 0);
  const int nkt = K >> 6;
  int cur = 0;
  for (int kt = 0; kt < nkt; ++kt) {
    __syncthreads();                   // stage(cur) landed; prev reads done
    if (kt + 1 < nkt) stage(cur ^ 1, kt + 1);
    const char* Al = (const char*)&As[cur][0];
    const char* Wl = (const char*)&Ws[cur][0];
#pragma unroll
    for (int kk = 0; kk < 2; ++kk) {
      bf16x8 af[4], wf[NJ];
#pragma unroll
      for (int i = 0; i < 4; ++i)
        af[i] = *(const bf16x8*)(Al + (wr * 64 + i * 16 + fr) * 128 +
                                 (((kk * 4 + fq) ^ (fr & 7)) << 4));
#pragma unroll
      for (int j = 0; j < NJ; ++j)
        wf[j] = *(const bf16x8*)(Wl + (wc * WN + j * 16 + fr) * 128 +
                                 (((kk * 4 + fq) ^ (fr & 7)) << 4));
#pragma unroll
      for (int i = 0; i < 4; ++i)
#pragma unroll
        for (int j = 0; j < NJ; ++j)
          acc[i][j] = mfma16(af[i], wf[j], acc[i][j]);
    }
    cur ^= 1;
  }

#pragma unroll
  for (int i = 0; i < 4; ++i) {
#pragma unroll
    for (int j = 0; j < NJ; ++j) {
#pragma unroll
      for (int r = 0; r < 4; ++r) {
        const int m = bm * 128 + wr * 64 + i * 16 + fq * 4 + r;
        const int n = bn * BN + wc * WN + j * 16 + fr;
        float v = acc[i][j][r] + bias[n];
        if (MODE == 0) {
          if (n < D_) v *= QSCALE;     // pre-scale Q for exp2-domain softmax
          Cbf[(size_t)m * N + n] = (bf16)v;
        } else if (MODE == 1) {
          float gl = 0.5f * v * (1.f + erff(v * 0.70710678118654752f));
          Cbf[(size_t)m * N + n] = (bf16)gl;
        } else {
          if (m < M_TOT) {
            const int b = m / KEEP, jj = m - b * KEEP;
            const int s = idx[b * KEEP + jj];
            resid[((size_t)(b * S_ + s)) * D_ + n] += gate[n] * v;
          }
        }
      }
    }
  }
}

// ---------------- flash attention: swapped-QK^T, in-register softmax ---------
__global__ __launch_bounds__(256) void k_attn(const bf16* __restrict__ qkv,
                                              bf16* __restrict__ out)
{
  __shared__ bf16 Klds[2][64 * 64];
  __shared__ bf16 Vlds[2][64 * 64];

  const int t = threadIdx.x;
  const int lane = t & 63, w = t >> 6;
  const int fr = lane & 15, fq = lane >> 4;
  const int qt = blockIdx.x, h = blockIdx.y, b = blockIdx.z;
  const size_t rowbase = (size_t)b * KEEP;
  const size_t RS = 3 * D_;
  const bf16* kbase = qkv + rowbase * RS + D_ + h * 64;
  const bf16* vbase = qkv + rowbase * RS + 2 * D_ + h * 64;

  const int wq0 = qt * 64 + w * 16;
  const int qrow = min(wq0 + fr, KEEP - 1);
  const bf16* qp = qkv + (rowbase + qrow) * RS + h * 64 + fq * 8;
  const bf16x8 qf0 = *(const bf16x8*)qp;          // Q as B-operand, d<32
  const bf16x8 qf1 = *(const bf16x8*)(qp + 32);   // d>=32

  f32x4 o[4] = {};
  float mrow = -INFINITY, lrow = 0.f;

  auto stage = [&](int buf, int kv) {
#pragma unroll
    for (int rnd = 0; rnd < 2; ++rnd) {
      const int p = rnd * 256 + t;
      {
        // K: row-major [64][64]; 16B-chunk XOR-swizzled by (row&7)^(row>>3)
        const int row = p >> 3, c8p = p & 7;
        const int c8 = c8p ^ ((row & 7) ^ (row >> 3));
        const int gr = min(kv + row, KEEP - 1);
        GLOAD_LDS(kbase + (size_t)gr * RS + c8 * 8, &Klds[buf][0] + p * 8);
      }
      {
        // V: subtiled [db][ksub][4][16] for tr-read
        const int db = p >> 7, ksub = (p >> 3) & 15, jr = (p >> 1) & 3,
                  c8lo = p & 1;
        const int vrow = ksub * 4 + jr, vc8 = db * 2 + c8lo;
        const int gr = min(kv + vrow, KEEP - 1);
        GLOAD_LDS(vbase + (size_t)gr * RS + vc8 * 8, &Vlds[buf][0] + p * 8);
      }
    }
  };

  stage(0, 0);
  int cur = 0;

  const unsigned vbase_lds0 =
      (unsigned)(size_t)(__attribute__((address_space(3))) bf16*)&Vlds[0][0];
  const unsigned vbase_lds1 =
      (unsigned)(size_t)(__attribute__((address_space(3))) bf16*)&Vlds[1][0];

  for (int ti = 0; ti < NKV; ++ti) {
    const int kv = ti * 64;
    __syncthreads();                   // stage(cur) landed; prev reads done
    if (ti + 1 < NKV) stage(cur ^ 1, kv + 64);

    const char* Kl = (const char*)&Klds[cur][0];

    // ---- S^T[k][q] fragments; fragment f covers k = sigma_f(i)
    f32x4 sc[4];
#pragma unroll
    for (int f = 0; f < 4; ++f) {
      const int row = ((f >> 1) << 5) + ((fr >> 2) << 3) + ((f & 1) << 1) +
                      (fr & 1) + (((fr >> 1) & 1) << 2);
      const int swz = (row & 7) ^ (row >> 3);
      const bf16x8 kf0 = *(const bf16x8*)(Kl + row * 128 + ((fq ^ swz) << 4));
      const bf16x8 kf1 =
          *(const bf16x8*)(Kl + row * 128 + (((fq ^ 4) ^ swz) << 4));
      f32x4 s = {0.f, 0.f, 0.f, 0.f};
      s = mfma16(kf0, qf0, s);   // A = K rows (k), B = Q cols (q)
      s = mfma16(kf1, qf1, s);
      sc[f] = s;
    }

    // ---- in-register online softmax for q = fr (lane-local row)
    if (ti == NKV - 1) {
#pragma unroll
      for (int f = 0; f < 4; ++f)
#pragma unroll
        for (int r = 0; r < 4; ++r) {
          const int kl = ((f >> 1) << 5) + (fq << 3) + ((f & 1) << 1) +
                         (r & 1) + ((r >> 1) << 2);
          if (kv + kl >= KEEP) sc[f][r] = -INFINITY;
        }
    }
    float mx = sc[0][0];
#pragma unroll
    for (int f = 0; f < 4; ++f)
#pragma unroll
      for (int r = 0; r < 4; ++r) mx = fmaxf(mx, sc[f][r]);
    mx = fmaxf(mx, __shfl_xor(mx, 16));
    mx = fmaxf(mx, __shfl_xor(mx, 32));
    const float mnew = fmaxf(mrow, mx);
    float ps = 0.f;
    bf16 pe[4][4];
#pragma unroll
    for (int f = 0; f < 4; ++f)
#pragma unroll
      for (int r = 0; r < 4; ++r) {
        const float pv = exp2f(sc[f][r] - mnew);
        ps += pv;
        pe[f][r] = (bf16)pv;
      }
    ps += __shfl_xor(ps, 16);
    ps += __shfl_xor(ps, 32);
    const float fac = exp2f(mrow - mnew);
    lrow = lrow * fac + ps;
    mrow = mnew;
#pragma unroll
    for (int db = 0; db < 4; ++db) {
      o[db][0] *= fac; o[db][1] *= fac; o[db][2] *= fac; o[db][3] *= fac;
    }

    // ---- PV: O^T = mfma(A = V^T via tr-read, B = P^T from registers)
    const bf16x8 pb[2] = {
        {pe[0][0], pe[0][1], pe[1][0], pe[1][1],
         pe[0][2], pe[0][3], pe[1][2], pe[1][3]},
        {pe[2][0], pe[2][1], pe[3][0], pe[3][1],
         pe[2][2], pe[2][3], pe[3][2], pe[3][3]}};
    const unsigned vb =
        (cur ? vbase_lds1 : vbase_lds0) + ((unsigned)fq << 7);
#pragma unroll
    for (int c = 0; c < 2; ++c) {
      const unsigned addr = vb + c * 1024;
      bf16x4 t0, t1, t2, t3, t4, t5, t6, t7;
      asm volatile(
          "ds_read_b64_tr_b16 %0, %8 offset:0\n\t"
          "ds_read_b64_tr_b16 %1, %8 offset:128\n\t"
          "ds_read_b64_tr_b16 %2, %8 offset:2048\n\t"
          "ds_read_b64_tr_b16 %3, %8 offset:2176\n\t"
          "ds_read_b64_tr_b16 %4, %8 offset:4096\n\t"
          "ds_read_b64_tr_b16 %5, %8 offset:4224\n\t"
          "ds_read_b64_tr_b16 %6, %8 offset:6144\n\t"
          "ds_read_b64_tr_b16 %7, %8 offset:6272\n\t"
          "s_waitcnt lgkmcnt(0)"
          : "=&v"(t0), "=&v"(t1), "=&v"(t2), "=&v"(t3),
            "=&v"(t4), "=&v"(t5), "=&v"(t6), "=&v"(t7)
          : "v"(addr));
      const bf16x8 vf0 = __builtin_shufflevector(t0, t1, 0, 1, 2, 3, 4, 5, 6, 7);
      const bf16x8 vf1 = __builtin_shufflevector(t2, t3, 0, 1, 2, 3, 4, 5, 6, 7);
      const bf16x8 vf2 = __builtin_shufflevector(t4, t5, 0, 1, 2, 3, 4, 5, 6, 7);
      const bf16x8 vf3 = __builtin_shufflevector(t6, t7, 0, 1, 2, 3, 4, 5, 6, 7);
      o[0] = mfma16(vf0, pb[c], o[0]);
      o[1] = mfma16(vf1, pb[c], o[1]);
      o[2] = mfma16(vf2, pb[c], o[2]);
      o[3] = mfma16(vf3, pb[c], o[3]);
    }
    cur ^= 1;
  }

  // ---- epilogue: lane fr owns q; O^T reg (db, r) -> d = db*16 + fq*4 + r
  const int q = wq0 + fr;
  if (q < KEEP) {
    const float inv = 1.f / lrow;
#pragma unroll
    for (int db = 0; db < 4; ++db) {
      bf16x4 wv = {(bf16)(o[db][0] * inv), (bf16)(o[db][1] * inv),
                   (bf16)(o[db][2] * inv), (bf16)(o[db][3] * inv)};
      *(bf16x4*)(out + (rowbase + q) * (size_t)D_ + h * 64 + db * 16 + fq * 4) =
          wv;
    }
  }
}

// ----------------------------------------------------------------------------
extern "C" void kernel_launch(void* const* d_in, const int* in_sizes, int n_in,
                              void* d_out, int out_size, void* d_ws, size_t ws_size,
                              hipStream_t stream)
{
  (void)in_sizes; (void)n_in; (void)out_size; (void)ws_size;
  const float* x      = (const float*)d_in[0];
  const float* t_emb  = (const float*)d_in[1];
  const float* tr_w1  = (const float*)d_in[2];
  const float* tr_b1  = (const float*)d_in[3];
  const float* tr_w2  = (const float*)d_in[4];
  const float* tr_b2  = (const float*)d_in[5];
  const float* ln1_w  = (const float*)d_in[6];
  const float* ln1_b  = (const float*)d_in[7];
  const float* ln2_w  = (const float*)d_in[8];
  const float* ln2_b  = (const float*)d_in[9];
  const float* in_w   = (const float*)d_in[10];
  const float* in_b   = (const float*)d_in[11];
  const float* out_w  = (const float*)d_in[12];
  const float* out_b  = (const float*)d_in[13];
  const float* f1_w   = (const float*)d_in[14];
  const float* f1_b   = (const float*)d_in[15];
  const float* f2_w   = (const float*)d_in[16];
  const float* f2_b   = (const float*)d_in[17];
  const float* gate_a = (const float*)d_in[18];
  const float* gate_f = (const float*)d_in[19];

  char* ws = (char*)d_ws;
  size_t off = 0;
  auto alloc = [&](size_t bytes) -> char* {
    char* p = ws + off;
    off = (off + bytes + 255) & ~(size_t)255;
    return p;
  };
  double* imp  = (double*)alloc((size_t)B_ * S_ * 8);
  double* hid  = (double*)alloc((size_t)B_ * S_ * 32 * 8);
  int* rank    = (int*)alloc((size_t)B_ * S_ * 4);
  int* idx     = (int*)alloc((size_t)B_ * KEEP * 4);
  float* p1    = (float*)alloc((size_t)B_ * 2 * D_ * 4);
  float* p2    = (float*)alloc((size_t)B_ * 2 * D_ * 4);
  bf16* w_in   = (bf16*)alloc((size_t)3 * D_ * D_ * 2);
  bf16* w_out  = (bf16*)alloc((size_t)D_ * D_ * 2);
  bf16* w_f1   = (bf16*)alloc((size_t)DFF_ * D_ * 2);
  bf16* w_f2   = (bf16*)alloc((size_t)D_ * DFF_ * 2);
  bf16* h_bf   = (bf16*)alloc((size_t)MPAD * D_ * 2);
  bf16* big    = (bf16*)alloc((size_t)MPAD * (3 * D_ + D_) * 2);
  bf16* qkv    = big;
  bf16* attn   = big + (size_t)MPAD * 3 * D_;
  bf16* ffn1   = big;   // overlays qkv+attn (both dead by then)

  hipMemcpyAsync(d_out, x, (size_t)B_ * S_ * D_ * 4, hipMemcpyDeviceToDevice, stream);

  k_impgemv<<<dim3(B_ * S_ / 16, 4), 256, 0, stream>>>(x, tr_w1, hid);
  k_imptail<<<B_ * S_ / 256, 256, 0, stream>>>(hid, tr_b1, tr_w2, tr_b2, imp);
  k_rank<<<B_ * 32, 256, 0, stream>>>(imp, rank);
  k_compact<<<B_, 256, 0, stream>>>(rank, idx);

  k_condproj<<<(B_ * 2 * D_) / 4, 256, 0, stream>>>(t_emb, ln1_w, ln1_b, p1);
  k_condproj<<<(B_ * 2 * D_) / 4, 256, 0, stream>>>(t_emb, ln2_w, ln2_b, p2);

  k_f2b<<<(3 * D_ * D_ / 4 + 255) / 256, 256, 0, stream>>>(in_w, w_in, 3 * D_ * D_ / 4);
  k_f2b<<<(D_ * D_ / 4 + 255) / 256, 256, 0, stream>>>(out_w, w_out, D_ * D_ / 4);
  k_f2b<<<(DFF_ * D_ / 4 + 255) / 256, 256, 0, stream>>>(f1_w, w_f1, DFF_ * D_ / 4);
  k_f2b<<<(DFF_ * D_ / 4 + 255) / 256, 256, 0, stream>>>(f2_w, w_f2, DFF_ * D_ / 4);

  k_adaln<<<MPAD, 256, 0, stream>>>(x, idx, p1, h_bf);
  k_gemm<128, 0><<<45 * 24, 256, 0, stream>>>(
      h_bf, w_in, in_b, qkv, nullptr, nullptr, nullptr, 3 * D_, D_, 24);
  k_attn<<<dim3(QT64, H_, B_), 256, 0, stream>>>(qkv, attn);
  k_gemm<64, 2><<<45 * 16, 256, 0, stream>>>(
      attn, w_out, out_b, nullptr, gate_a, idx, (float*)d_out, D_, D_, 16);
  k_adaln<<<MPAD, 256, 0, stream>>>((const float*)d_out, idx, p2, h_bf);
  k_gemm<128, 1><<<45 * 32, 256, 0, stream>>>(
      h_bf, w_f1, f1_b, ffn1, nullptr, nullptr, nullptr, DFF_, D_, 32);
  k_gemm<64, 2><<<45 * 16, 256, 0, stream>>>(
      ffn1, w_f2, f2_b, nullptr, gate_f, idx, (float*)d_out, D_, DFF_, 16);
}